// Round 1
// 402.311 us; speedup vs baseline: 1.0842x; 1.0842x over previous
//
#include <hip/hip_runtime.h>
#include <hip/hip_bf16.h>
#include <math.h>

#define HH 226
#define WW 226
#define HWIMG (226*226)
#define PS 16
#define STP 14
#define TOK 256
#define NPATCH 512
#define NTOK (NPATCH*TOK)
#define OUT_ELEMS (2*64*226*226)

typedef unsigned int u32;
typedef unsigned short u16;
typedef __attribute__((ext_vector_type(8))) short short8;
typedef __attribute__((ext_vector_type(4))) float f32x4;

__device__ __forceinline__ float lo16(u32 u){ return __uint_as_float(u << 16); }
__device__ __forceinline__ float hi16(u32 u){ return __uint_as_float(u & 0xFFFF0000u); }
__device__ __forceinline__ u16 f2bf(float f){
    u32 u = __float_as_uint(f);
    u += 0x7FFFu + ((u >> 16) & 1u);
    return (u16)(u >> 16);
}
__device__ __forceinline__ u32 pack2(float a, float b){
#if defined(__gfx950__) && __has_builtin(__builtin_amdgcn_cvt_pk_bf16_f32)
    auto r = __builtin_amdgcn_cvt_pk_bf16_f32(a, b);   // v_cvt_pk_bf16_f32 (RNE)
    return *(u32*)&r;
#else
    return (u32)f2bf(a) | ((u32)f2bf(b) << 16);
#endif
}
__device__ __forceinline__ float fexp2(float x){
#if __has_builtin(__builtin_amdgcn_exp2f)
    return __builtin_amdgcn_exp2f(x);                  // single v_exp_f32
#else
    return exp2f(x);
#endif
}
__device__ __forceinline__ void unpack8(uint4 r, float* d){
    d[0]=lo16(r.x); d[1]=hi16(r.x); d[2]=lo16(r.y); d[3]=hi16(r.y);
    d[4]=lo16(r.z); d[5]=hi16(r.z); d[6]=lo16(r.w); d[7]=hi16(r.w);
}
__device__ __forceinline__ uint4 pack8(const float* a){
    uint4 uu;
    uu.x = pack2(a[0], a[1]);
    uu.y = pack2(a[2], a[3]);
    uu.z = pack2(a[4], a[5]);
    uu.w = pack2(a[6], a[7]);
    return uu;
}
__device__ __forceinline__ float gelu_f(float x){
    return 0.5f * x * (1.0f + erff(x * 0.70710678118654752f));
}

template<int N>
__device__ __forceinline__ void store_bf16(u32* dst, const float* a){
    uint4* p4 = (uint4*)(dst);
    #pragma unroll
    for (int w4 = 0; w4 < N/8; ++w4) p4[w4] = pack8(a + 8*w4);
}

// ---------------- K0: transpose wq/wk/wv -> bf16 [n][k] (B-frag friendly) ----------------
__global__ __launch_bounds__(256, 4) void k0_wt(
    const float* __restrict__ wq, const float* __restrict__ wk,
    const float* __restrict__ wv, u16* __restrict__ wt)
{
    const int i = blockIdx.x*256 + threadIdx.x;     // 48 blocks * 256 = 12288
    const int m = i >> 12, rem = i & 4095;
    const int kk = rem >> 6, n = rem & 63;          // consecutive tid -> consecutive n (coalesced read)
    const float* w = (m==0 ? wq : (m==1 ? wk : wv));
    wt[m*4096 + n*64 + kk] = f2bf(w[kk*64 + n]);
}

// ---------------- K1: patch gather + LN1 (LDS) + MFMA QKV ----------------
// Phase A: 2 threads/token gather x, LN1 via pair-shuffle, normalized bf16 -> ys
//          (row stride 72 u16 = 144 B, 16B-aligned for ds_read_b128).
// Phase B: 8 waves x 2 m-tiles; per matrix: B-frags = global b128 loads of the
//          k0-transposed weights (L1-hot), 8 MFMAs, pair-pack -> per-wave strip,
//          fully-coalesced 256B stores of q/k/v.
// NOTE: q is pre-scaled by 0.25*log2(e) so k2's softmax exp2 needs no multiply.
__global__ __launch_bounds__(512, 4) void k1_qkv(
    const float* __restrict__ x, const float* __restrict__ g1, const float* __restrict__ b1,
    const u16* __restrict__ wt,
    float* __restrict__ t_out, u32* __restrict__ qo, u32* __restrict__ ko, u32* __restrict__ vo)
{
    __shared__ u16 ys[256*72];           // [tok][72 u16]: 64 ch + 8 pad
    __shared__ u32 strip[8][16*34];      // per-wave 16 rows x (32 u32 + 2 pad)
    __shared__ float g_s[64], b_s[64];
    const int tid = threadIdx.x;
    if (tid < 64){ g_s[tid]=g1[tid]; b_s[tid]=b1[tid]; }

    const int p = blockIdx.x;
    const int bi = p >> 8, ph = (p >> 4) & 15, pw = p & 15;

    // ---- Phase A ----
    const int tok = tid >> 1, h = tid & 1;
    const int ti = tok >> 4, tj = tok & 15;
    const int r = ph*STP + ti, c = pw*STP + tj;
    const float* xb = x + ((size_t)bi*64 + 32*h)*HWIMG + (size_t)r*WW + c;
    const size_t gtokA = (size_t)p*TOK + tok;
    float* tp = t_out + gtokA*64 + 32*h;

    float v32[32];
    float s1 = 0.f, s2 = 0.f;
    #pragma unroll
    for (int c8 = 0; c8 < 4; ++c8){
        #pragma unroll
        for (int u = 0; u < 8; ++u){
            const float vv = xb[(size_t)(c8*8+u)*HWIMG];
            v32[c8*8+u] = vv;
            s1 += vv; s2 += vv*vv;
        }
        ((float4*)tp)[c8*2]   = make_float4(v32[c8*8+0],v32[c8*8+1],v32[c8*8+2],v32[c8*8+3]);
        ((float4*)tp)[c8*2+1] = make_float4(v32[c8*8+4],v32[c8*8+5],v32[c8*8+6],v32[c8*8+7]);
    }
    s1 += __shfl_xor(s1, 1);
    s2 += __shfl_xor(s2, 1);
    const float mu = s1 * (1.f/64.f);
    const float var = s2 * (1.f/64.f) - mu*mu;
    const float rs = rsqrtf(var + 1e-5f);
    __syncthreads();                      // g_s ready
    u32* ysw = (u32*)ys;
    #pragma unroll
    for (int i2 = 0; i2 < 16; ++i2){
        const int kk = 32*h + 2*i2;
        const float a0 = (v32[2*i2]  -mu)*rs*g_s[kk]   + b_s[kk];
        const float a1 = (v32[2*i2+1]-mu)*rs*g_s[kk+1] + b_s[kk+1];
        ysw[tok*36 + 16*h + i2] = pack2(a0, a1);
    }
    __syncthreads();                      // ys ready

    // ---- Phase B ----
    const int lane = tid & 63;
    const int w8   = tid >> 6;           // wave 0..7
    const int c15  = lane & 15;
    const int quad = lane >> 4;
    u32* stw = strip[w8];
    const size_t ptok = (size_t)p * TOK;

    for (int mt = 0; mt < 2; ++mt){
        const int T = w8*32 + mt*16;     // m-tile token base
        short8 af[2];
        #pragma unroll
        for (int kb = 0; kb < 2; ++kb)
            af[kb] = *(const short8*)(ys + (T + c15)*72 + kb*32 + quad*8);

        #pragma unroll
        for (int m = 0; m < 3; ++m){
            // B-frags for this matrix (b128 loads, L1/L2-hot)
            short8 bf[2][4];
            #pragma unroll
            for (int kb = 0; kb < 2; ++kb)
                #pragma unroll
                for (int nt = 0; nt < 4; ++nt)
                    bf[kb][nt] = *(const short8*)(wt + m*4096 + (nt*16 + c15)*64 + kb*32 + quad*8);

            f32x4 C[4];
            #pragma unroll
            for (int nt = 0; nt < 4; ++nt) C[nt] = (f32x4){0.f,0.f,0.f,0.f};
            #pragma unroll
            for (int kb = 0; kb < 2; ++kb)
                #pragma unroll
                for (int nt = 0; nt < 4; ++nt)
                    C[nt] = __builtin_amdgcn_mfma_f32_16x16x32_bf16(af[kb], bf[kb][nt], C[nt], 0, 0, 0);

            // fold softmax scale (dh^-0.5 * log2e) into q
            if (m == 0){
                #pragma unroll
                for (int nt = 0; nt < 4; ++nt)
                    #pragma unroll
                    for (int rr = 0; rr < 4; ++rr)
                        C[nt][rr] *= 0.3606737602222409f;
            }

            // pair-pack C tiles -> strip (b32 writes, <=2-way banks)
            #pragma unroll
            for (int nt = 0; nt < 4; ++nt){
                #pragma unroll
                for (int r2 = 0; r2 < 2; ++r2){
                    const float pv0 = __shfl_xor(C[nt][2*r2],   1);
                    const float pv1 = __shfl_xor(C[nt][2*r2+1], 1);
                    u32 wrd; int row;
                    if ((lane & 1) == 0){ wrd = pack2(C[nt][2*r2], pv0);  row = quad*4 + 2*r2; }
                    else                { wrd = pack2(pv1, C[nt][2*r2+1]); row = quad*4 + 2*r2 + 1; }
                    stw[row*34 + nt*8 + (c15 >> 1)] = wrd;
                }
            }

            // coalesced store: 8 insts x 64 lanes x 4B = 16 token rows
            u32* om = (m==0 ? qo : (m==1 ? ko : vo));
            #pragma unroll
            for (int i = 0; i < 8; ++i){
                const int flat = i*64 + lane;
                const u32 wv = stw[(flat >> 5)*34 + (flat & 31)];
                om[(ptok + T)*32 + flat] = wv;
            }
        }
    }
}

// ---------------- K2: MFMA attention (swapped QK^T), 2 blocks/patch, wave = head ----------------
// S^T = mfma(K, Q): col = q-token (lane&15) -> each lane owns one full q-row of P.
// P->LDS pack is pure in-lane cvt_pk (no shuffles); row-sum is in-lane + 2 shfl_xor.
// K and V frags RESIDENT in VGPRs. Grid split 2x over q-tiles -> 4 blocks/CU occupancy.
__global__ __launch_bounds__(256, 2) void k2_attn(
    const u16* __restrict__ qg, const u16* __restrict__ kg,
    const u16* __restrict__ vg, u16* __restrict__ og)   // og aliases qg
{
    __shared__ u16 plds[4][16*280];      // per-wave 16 q-rows x 280 u16 (560B stride)
    const int tid  = threadIdx.x;
    const int lane = tid & 63;
    const int h    = tid >> 6;           // wave = head
    const int pb   = blockIdx.x;
    const int p    = pb >> 1;            // patch
    const int half = pb & 1;             // q-tile half (0: qt 0-7, 1: qt 8-15)
    const int c15  = lane & 15;
    const int quad = lane >> 4;
    const size_t pbase = (size_t)p * TOK * 64;   // u16 elements

    // K A-frags resident (16 tiles; quads 2,3 = K-dim zero pad)
    short8 kf[16];
    #pragma unroll
    for (int t = 0; t < 16; ++t){
        short8 bf = {0,0,0,0,0,0,0,0};
        if (quad < 2)
            bf = *(const short8*)(kg + pbase + (size_t)(t*16 + c15)*64 + h*16 + quad*8);
        kf[t] = bf;
    }
    // V B-frags resident: vf[kb][j] = V[kb*32+quad*8+j][h*16+c15]
    short8 vf[8];
    #pragma unroll
    for (int kb = 0; kb < 8; ++kb){
        #pragma unroll
        for (int j = 0; j < 8; ++j)
            vf[kb][j] = (short)vg[pbase + (size_t)(kb*32 + quad*8 + j)*64 + h*16 + c15];
    }
    u16* pw  = &plds[h][0];
    u32* pwq = (u32*)pw + c15*140;       // this lane's q-row base (word units)

    for (int qi = 0; qi < 8; ++qi){
        const int qt = half*8 + qi;

        // Q B-frag (quads 2,3 are the K-pad -> zero); q pre-scaled in k1
        short8 qf = {0,0,0,0,0,0,0,0};
        if (quad < 2)
            qf = *(const short8*)(qg + pbase + (size_t)(qt*16 + c15)*64 + h*16 + quad*8);

        // S^T = K . Q^T : 16 k-tiles; lane holds P^T[k=t*16+quad*4+r][q=c15]
        f32x4 St[16];
        #pragma unroll
        for (int t = 0; t < 16; ++t){
            f32x4 z = {0.f,0.f,0.f,0.f};
            St[t] = __builtin_amdgcn_mfma_f32_16x16x32_bf16(kf[t], qf, z, 0, 0, 0);
        }

        // exp2 (scale folded into q); in-lane partial row sums
        float rsm[4] = {0.f,0.f,0.f,0.f};
        #pragma unroll
        for (int t = 0; t < 16; ++t){
            #pragma unroll
            for (int r = 0; r < 4; ++r){
                const float pe = fexp2(St[t][r]);
                St[t][r] = pe;
                rsm[r] += pe;
            }
        }
        float s = (rsm[0]+rsm[1]) + (rsm[2]+rsm[3]);
        s += __shfl_xor(s, 16);
        s += __shfl_xor(s, 32);
        const float rinv = __builtin_amdgcn_rcpf(s);
        float rv[4];
        #pragma unroll
        for (int r = 0; r < 4; ++r) rv[r] = __shfl(rinv, quad*4 + r);   // rinv for q-row quad*4+r

        // P -> LDS (bf16, unnormalized): adjacent k pairs are in-lane -> pure cvt_pk + b64 write
        #pragma unroll
        for (int t = 0; t < 16; ++t){
            uint2 wr;
            wr.x = pack2(St[t][0], St[t][1]);
            wr.y = pack2(St[t][2], St[t][3]);
            *(uint2*)(pwq + t*8 + quad*2) = wr;    // row c15, k-offset t*16+quad*4
        }

        // PV: O[q][d], A = P from LDS, B = resident V frags; two chains for ILP
        f32x4 O0 = {0.f,0.f,0.f,0.f}, O1 = {0.f,0.f,0.f,0.f};
        #pragma unroll
        for (int kb = 0; kb < 4; ++kb){
            const short8 a0 = *(const short8*)(pw + c15*280 + (2*kb)*32 + quad*8);
            const short8 a1 = *(const short8*)(pw + c15*280 + (2*kb+1)*32 + quad*8);
            O0 = __builtin_amdgcn_mfma_f32_16x16x32_bf16(a0, vf[2*kb],   O0, 0, 0, 0);
            O1 = __builtin_amdgcn_mfma_f32_16x16x32_bf16(a1, vf[2*kb+1], O1, 0, 0, 0);
        }

        // normalize rows by softmax sum (rcp) and store
        #pragma unroll
        for (int r = 0; r < 4; ++r){
            const float ov = (O0[r] + O1[r]) * rv[r];
            og[pbase + (size_t)(qt*16 + quad*4 + r)*64 + h*16 + c15] = f2bf(ov);
        }
    }
}

// ---------------- K3: MFMA proj + residual + LN2 + fc1 + GELU ----------------
__global__ __launch_bounds__(256, 2) void k3_proj_fc1(
    const u16* __restrict__ og, float* __restrict__ t,
    const float* __restrict__ wp, const float* __restrict__ bp,
    const float* __restrict__ g2, const float* __restrict__ b2,
    const float* __restrict__ wf1, const float* __restrict__ bf1,
    u32* __restrict__ y3)
{
    __shared__ u16 strip[4][16*136];     // per-wave: 16 rows x 136 u16 (272B stride)
    __shared__ float bp_s[64], g_s[64], b_s[64], bf_s[128];
    const int tid  = threadIdx.x;
    const int lane = tid & 63;
    const int w    = tid >> 6;
    const int c15  = lane & 15;
    const int quad = lane >> 4;
    if (tid < 64){ bp_s[tid]=bp[tid]; g_s[tid]=g2[tid]; b_s[tid]=b2[tid]; }
    else if (tid >= 128){ const int j = tid - 128; bf_s[j] = bf1[j]; }
    __syncthreads();

    // resident B-frags (bf16): wp 2kb x 4nt, wf1 2kb x 8nt
    short8 wpf[2][4];
    short8 wff[2][8];
    #pragma unroll
    for (int kb = 0; kb < 2; ++kb){
        #pragma unroll
        for (int nt = 0; nt < 4; ++nt){
            #pragma unroll
            for (int j = 0; j < 8; ++j)
                wpf[kb][nt][j] = (short)f2bf(wp[(kb*32 + quad*8 + j)*64 + nt*16 + c15]);
        }
        #pragma unroll
        for (int nt = 0; nt < 8; ++nt){
            #pragma unroll
            for (int j = 0; j < 8; ++j)
                wff[kb][nt][j] = (short)f2bf(wf1[(kb*32 + quad*8 + j)*128 + nt*16 + c15]);
        }
    }

    const int p = blockIdx.x;
    const size_t pbase = (size_t)p * TOK;           // token index base
    u16* st = strip[w];
    u32* stw = (u32*)st;

    const float gch[4] = { g_s[0*16+c15], g_s[1*16+c15], g_s[2*16+c15], g_s[3*16+c15] };
    const float bch[4] = { b_s[0*16+c15], b_s[1*16+c15], b_s[2*16+c15], b_s[3*16+c15] };
    const float bpc[4] = { bp_s[0*16+c15], bp_s[1*16+c15], bp_s[2*16+c15], bp_s[3*16+c15] };

    for (int rt = 0; rt < 4; ++rt){
        const int T = w*64 + rt*16;                 // m-tile token base

        // proj A-frags
        short8 af[2];
        #pragma unroll
        for (int kb = 0; kb < 2; ++kb)
            af[kb] = *(const short8*)(og + (pbase + T + c15)*64 + kb*32 + quad*8);

        // proj MFMA (bias init)
        f32x4 C[4];
        #pragma unroll
        for (int nt = 0; nt < 4; ++nt){
            const float b = bpc[nt];
            C[nt] = (f32x4){b, b, b, b};
        }
        #pragma unroll
        for (int kb = 0; kb < 2; ++kb)
            #pragma unroll
            for (int nt = 0; nt < 4; ++nt)
                C[nt] = __builtin_amdgcn_mfma_f32_16x16x32_bf16(af[kb], wpf[kb][nt], C[nt], 0, 0, 0);

        // residual add + t2 store (64B segments)
        #pragma unroll
        for (int nt = 0; nt < 4; ++nt){
            #pragma unroll
            for (int r = 0; r < 4; ++r)
                C[nt][r] += t[(pbase + T + quad*4 + r)*64 + nt*16 + c15];
        }
        #pragma unroll
        for (int nt = 0; nt < 4; ++nt){
            #pragma unroll
            for (int r = 0; r < 4; ++r)
                t[(pbase + T + quad*4 + r)*64 + nt*16 + c15] = C[nt][r];
        }

        // LN2 row stats (row = quad*4 + r)
        float rs1[4] = {0,0,0,0}, rs2[4] = {0,0,0,0};
        #pragma unroll
        for (int nt = 0; nt < 4; ++nt)
            #pragma unroll
            for (int r = 0; r < 4; ++r){ rs1[r] += C[nt][r]; rs2[r] += C[nt][r]*C[nt][r]; }
        #pragma unroll
        for (int r = 0; r < 4; ++r){
            rs1[r] += __shfl_xor(rs1[r], 1); rs2[r] += __shfl_xor(rs2[r], 1);
            rs1[r] += __shfl_xor(rs1[r], 2); rs2[r] += __shfl_xor(rs2[r], 2);
            rs1[r] += __shfl_xor(rs1[r], 4); rs2[r] += __shfl_xor(rs2[r], 4);
            rs1[r] += __shfl_xor(rs1[r], 8); rs2[r] += __shfl_xor(rs2[r], 8);
        }
        float muv[4], rsg[4];
        #pragma unroll
        for (int r = 0; r < 4; ++r){
            muv[r] = rs1[r]*(1.f/64.f);
            const float var = rs2[r]*(1.f/64.f) - muv[r]*muv[r];
            rsg[r] = rsqrtf(var + 1e-5f);
        }

        // normalized y -> strip (bf16, pair-packed b32 writes)
        #pragma unroll
        for (int nt = 0; nt < 4; ++nt){
            float yv[4];
            #pragma unroll
            for (int r = 0; r < 4; ++r)
                yv[r] = (C[nt][r]-muv[r])*rsg[r]*gch[nt] + bch[nt];
            #pragma unroll
            for (int r2 = 0; r2 < 2; ++r2){
                const float pv0 = __shfl_xor(yv[2*r2],   1);
                const float pv1 = __shfl_xor(yv[2*r2+1], 1);
                u32 wrd; int row;
                if ((lane & 1) == 0){ wrd = pack2(yv[2*r2], pv0);  row = quad*4 + 2*r2; }
                else                { wrd = pack2(pv1, yv[2*r2+1]); row = quad*4 + 2*r2 + 1; }
                *(u32*)(st + row*136 + nt*16 + (c15 & ~1)) = wrd;
            }
        }

        // fc1 A-frags from strip
        short8 pa[2];
        #pragma unroll
        for (int kb = 0; kb < 2; ++kb)
            pa[kb] = *(const short8*)(st + c15*136 + kb*32 + quad*8);

        // fc1 MFMA (bias init)
        f32x4 F[8];
        #pragma unroll
        for (int nt = 0; nt < 8; ++nt){
            const float b = bf_s[nt*16 + c15];
            F[nt] = (f32x4){b, b, b, b};
        }
        #pragma unroll
        for (int kb = 0; kb < 2; ++kb)
            #pragma unroll
            for (int nt = 0; nt < 8; ++nt)
                F[nt] = __builtin_amdgcn_mfma_f32_16x16x32_bf16(pa[kb], wff[kb][nt], F[nt], 0, 0, 0);

        // GELU
        #pragma unroll
        for (int nt = 0; nt < 8; ++nt)
            #pragma unroll
            for (int r = 0; r < 4; ++r)
                F[nt][r] = gelu_f(F[nt][r]);

        // y3 tile -> strip (pair-packed bf16)
        #pragma unroll
        for (int nt = 0; nt < 8; ++nt){
            #pragma unroll
            for (int r2 = 0; r2 < 2; ++r2){
                const float pv0 = __shfl_xor(F[nt][2*r2],   1);
                const float pv1 = __shfl_xor(F[nt][2*r2+1], 1);
                u32 wrd; int row;
                if ((lane & 1) == 0){ wrd = pack2(F[nt][2*r2], pv0);  row = quad*4 + 2*r2; }
                else                { wrd = pack2(pv1, F[nt][2*r2+1]); row = quad*4 + 2*r2 + 1; }
                *(u32*)(st + row*136 + nt*16 + (c15 & ~1)) = wrd;
            }
        }
        // coalesced y3 store: inst i covers token T+i, 64 u32 = 256B contiguous
        #pragma unroll
        for (int i = 0; i < 16; ++i){
            const u32 wv = stw[i*68 + lane];
            y3[(pbase + T + i)*64 + lane] = wv;
        }
    }
}

// ---------------- K4a: depthwise 5x5 conv + GELU + add (in-place on y3) ----------------
__global__ __launch_bounds__(256, 2) void k4a_dwconv(
    u32* y3, const float* __restrict__ wdw, const float* __restrict__ bdw)
{
    __shared__ u32 ys[400*33];       // 20x20 zero halo, 64 ch (32 words) + 1 pad
    __shared__ float wdwT[25*64];
    __shared__ float bdw_s[64];
    const int tid = threadIdx.x;
    const int p = blockIdx.x;
    const int ti = tid >> 4, tj = tid & 15;
    const int stok = (ti+2)*20 + (tj+2);
    const size_t gtok = (size_t)p*TOK + tid;
    for (int i = tid; i < 13200; i += 256) ys[i] = 0u;
    for (int half = 0; half < 2; ++half){
        __syncthreads();   // protect zero-init / previous phase reads
        for (int i = tid; i < 1600; i += 256){
            int chh = i/25, tap = i%25;
            wdwT[tap*64+chh] = wdw[(half*64+chh)*25 + tap];
        }
        if (tid < 64) bdw_s[tid] = bdw[half*64+tid];
        {
            const uint4* gp = (const uint4*)(y3 + gtok*64 + half*32);
            #pragma unroll
            for (int w = 0; w < 8; ++w){
                uint4 rr = gp[w];
                ys[stok*33 + w*4+0]=rr.x; ys[stok*33 + w*4+1]=rr.y;
                ys[stok*33 + w*4+2]=rr.z; ys[stok*33 + w*4+3]=rr.w;
            }
        }
        __syncthreads();
        const int base = stok*33;
        for (int ch2 = 0; ch2 < 32; ++ch2){
            float a0 = bdw_s[2*ch2], a1 = bdw_s[2*ch2+1];
            #pragma unroll
            for (int tap = 0; tap < 25; ++tap){
                const int di = tap/5, dj = tap%5;
                const int woff = ((di-2)*20 + (dj-2))*33;
                const u32 w0 = ys[base + woff + ch2];
                a0 += lo16(w0)*wdwT[tap*64+2*ch2];
                a1 += hi16(w0)*wdwT[tap*64+2*ch2+1];
            }
            const u32 own = ys[base + ch2];
            const float o0 = lo16(own) + gelu_f(a0);
            const float o1 = hi16(own) + gelu_f(a1);
            y3[gtok*64 + half*32 + ch2] = pack2(o0, o1);
        }
    }
}

// ---------------- K4b: fc2 + residual -> t3 [patch][ch][tok] ----------------
__global__ __launch_bounds__(256, 4) void k4b_fc2(
    const u32* __restrict__ y3, const float* __restrict__ t2,
    const float* __restrict__ wf2, const float* __restrict__ bf2,
    float* __restrict__ t3)
{
    __shared__ float wf_s[8192];
    __shared__ float bf_s[64];
    const int tid = threadIdx.x;
    for (int i = tid; i < 8192; i += 256) wf_s[i] = wf2[i];
    if (tid < 64) bf_s[tid] = bf2[tid];
    __syncthreads();
    const int p = blockIdx.x;
    const size_t gtok = (size_t)p*TOK + tid;
    float acc[64];
    #pragma unroll
    for (int d = 0; d < 64; ++d) acc[d] = bf_s[d];
    const uint4* yp = (const uint4*)(y3 + gtok*64);
    for (int c8 = 0; c8 < 16; ++c8){
        float a8[8]; unpack8(yp[c8], a8);
        #pragma unroll
        for (int u = 0; u < 8; ++u){
            const float a = a8[u];
            const float* wr = wf_s + (c8*8+u)*64;
            #pragma unroll
            for (int d = 0; d < 64; ++d) acc[d] += a*wr[d];
        }
    }
    const float* tp = t2 + gtok*64;
    #pragma unroll
    for (int q4 = 0; q4 < 16; ++q4){
        float4 tv = ((const float4*)tp)[q4];
        acc[q4*4+0]+=tv.x; acc[q4*4+1]+=tv.y; acc[q4*4+2]+=tv.z; acc[q4*4+3]+=tv.w;
    }
    float* t3p = t3 + (size_t)p*16384 + tid;
    #pragma unroll
    for (int d = 0; d < 64; ++d) t3p[d*256] = acc[d];
}

// ---------------- K5: overlap-add gather + averaging ----------------
__global__ __launch_bounds__(256, 4) void k5_reverse(
    const float* __restrict__ t3, float* __restrict__ out)
{
    const int e = blockIdx.x*256 + threadIdx.x;
    if (e >= OUT_ELEMS) return;
    const int c = e % WW;
    int tmp = e / WW;
    const int r = tmp % HH;
    tmp /= HH;
    const int ch = tmp & 63;
    const int b = tmp >> 6;
    int pr = r/14; if (pr > 15) pr = 15;
    int pc = c/14; if (pc > 15) pc = 15;
    const int ra = r - pr*14, ca = c - pc*14;
    const int rb = ra + 14, cb = ca + 14;
    const bool hr = (pr >= 1) && (rb < 16);
    const bool hc = (pc >= 1) && (cb < 16);
    #define T3IDX(PH,PC,I,J) (((((b*16+(PH))*16+(PC))*64 + ch) << 8) + (I)*16 + (J))
    float s = t3[T3IDX(pr,pc,ra,ca)];
    if (hr)       s += t3[T3IDX(pr-1,pc,  rb,ca)];
    if (hc)       s += t3[T3IDX(pr,  pc-1,ra,cb)];
    if (hr && hc) s += t3[T3IDX(pr-1,pc-1,rb,cb)];
    const float f = (hr ? 0.5f : 1.f) * (hc ? 0.5f : 1.f);
    out[e] = s * f;
    #undef T3IDX
}

extern "C" void kernel_launch(void* const* d_in, const int* in_sizes, int n_in,
                              void* d_out, int out_size, void* d_ws, size_t ws_size,
                              hipStream_t stream)
{
    const float* x    = (const float*)d_in[0];
    const float* g1   = (const float*)d_in[1];
    const float* b1   = (const float*)d_in[2];
    const float* wq   = (const float*)d_in[3];
    const float* wk   = (const float*)d_in[4];
    const float* wv   = (const float*)d_in[5];
    const float* wp   = (const float*)d_in[6];
    const float* bp   = (const float*)d_in[7];
    const float* g2   = (const float*)d_in[8];
    const float* b2   = (const float*)d_in[9];
    const float* wf1  = (const float*)d_in[10];
    const float* bf1  = (const float*)d_in[11];
    const float* wdw  = (const float*)d_in[12];
    const float* bdw  = (const float*)d_in[13];
    const float* wf2  = (const float*)d_in[14];
    const float* bf2  = (const float*)d_in[15];

    char* ws = (char*)d_ws;
    // layout (bytes):
    //   [0,        33554432)  t   fp32  (becomes t2 in-place in k3)
    //   [33554432, 50331648)  q   bf16  (k2 output o overwrites it)
    //   [50331648, 67108864)  k   bf16  \  t3 fp32 aliases k+v after k2
    //   [67108864, 83886080)  v   bf16  /
    //   [83886080, 117440512) y3  bf16  (128/token; k4a updates in place)
    // wt (transposed bf16 qkv weights, 24 KB) lives at the head of d_out —
    // consumed by k1, fully overwritten by k5 at the end.
    float* t  = (float*)(ws);
    u32* q    = (u32*)(ws + 33554432);
    u32* k    = (u32*)(ws + 50331648);
    u32* v    = (u32*)(ws + 67108864);
    float* t3 = (float*)(ws + 50331648);
    u32* y3   = (u32*)(ws + 83886080);
    u16* wt   = (u16*)d_out;
    float* out = (float*)d_out;

    k0_wt      <<<48,        256, 0, stream>>>(wq, wk, wv, wt);
    k1_qkv     <<<NPATCH,    512, 0, stream>>>(x, g1, b1, wt, t, q, k, v);
    k2_attn    <<<NPATCH*2,  256, 0, stream>>>((const u16*)q, (const u16*)k, (const u16*)v, (u16*)q);
    k3_proj_fc1<<<NPATCH,    256, 0, stream>>>((const u16*)q, t, wp, bp, g2, b2, wf1, bf1, y3);
    k4a_dwconv <<<NPATCH,    256, 0, stream>>>(y3, wdw, bdw);
    k4b_fc2    <<<NPATCH,    256, 0, stream>>>(y3, t, wf2, bf2, t3);
    k5_reverse <<<25538,     256, 0, stream>>>(t3, out);
}

// Round 3
// 348.721 us; speedup vs baseline: 1.2508x; 1.1537x over previous
//
#include <hip/hip_runtime.h>
#include <hip/hip_bf16.h>
#include <math.h>

#define HH 226
#define WW 226
#define HWIMG (226*226)
#define PS 16
#define STP 14
#define TOK 256
#define NPATCH 512
#define NTOK (NPATCH*TOK)
#define OUT_ELEMS (2*64*226*226)

typedef unsigned int u32;
typedef unsigned short u16;
typedef __attribute__((ext_vector_type(8))) short short8;
typedef __attribute__((ext_vector_type(4))) float f32x4;

__device__ __forceinline__ float lo16(u32 u){ return __uint_as_float(u << 16); }
__device__ __forceinline__ float hi16(u32 u){ return __uint_as_float(u & 0xFFFF0000u); }
__device__ __forceinline__ u16 f2bf(float f){
    u32 u = __float_as_uint(f);
    u += 0x7FFFu + ((u >> 16) & 1u);
    return (u16)(u >> 16);
}
__device__ __forceinline__ u32 pack2(float a, float b){
#if defined(__gfx950__) && __has_builtin(__builtin_amdgcn_cvt_pk_bf16_f32)
    auto r = __builtin_amdgcn_cvt_pk_bf16_f32(a, b);   // v_cvt_pk_bf16_f32 (RNE)
    return *(u32*)&r;
#else
    return (u32)f2bf(a) | ((u32)f2bf(b) << 16);
#endif
}
__device__ __forceinline__ float fexp2(float x){
#if __has_builtin(__builtin_amdgcn_exp2f)
    return __builtin_amdgcn_exp2f(x);                  // single v_exp_f32
#else
    return exp2f(x);
#endif
}
__device__ __forceinline__ void unpack8(uint4 r, float* d){
    d[0]=lo16(r.x); d[1]=hi16(r.x); d[2]=lo16(r.y); d[3]=hi16(r.y);
    d[4]=lo16(r.z); d[5]=hi16(r.z); d[6]=lo16(r.w); d[7]=hi16(r.w);
}
__device__ __forceinline__ uint4 pack8(const float* a){
    uint4 uu;
    uu.x = pack2(a[0], a[1]);
    uu.y = pack2(a[2], a[3]);
    uu.z = pack2(a[4], a[5]);
    uu.w = pack2(a[6], a[7]);
    return uu;
}
__device__ __forceinline__ float gelu_f(float x){
    return 0.5f * x * (1.0f + erff(x * 0.70710678118654752f));
}

template<int N>
__device__ __forceinline__ void store_bf16(u32* dst, const float* a){
    uint4* p4 = (uint4*)(dst);
    #pragma unroll
    for (int w4 = 0; w4 < N/8; ++w4) p4[w4] = pack8(a + 8*w4);
}

// ---------------- K0: transpose wq/wk/wv -> bf16 [n][k] (B-frag friendly) ----------------
__global__ __launch_bounds__(256, 4) void k0_wt(
    const float* __restrict__ wq, const float* __restrict__ wk,
    const float* __restrict__ wv, u16* __restrict__ wt)
{
    const int i = blockIdx.x*256 + threadIdx.x;     // 48 blocks * 256 = 12288
    const int m = i >> 12, rem = i & 4095;
    const int kk = rem >> 6, n = rem & 63;          // consecutive tid -> consecutive n (coalesced read)
    const float* w = (m==0 ? wq : (m==1 ? wk : wv));
    wt[m*4096 + n*64 + kk] = f2bf(w[kk*64 + n]);
}

// ---------------- K1: patch gather + LN1 (LDS) + MFMA QKV ----------------
// Phase A: 2 threads/token gather x, LN1 via pair-shuffle, normalized bf16 -> ys
//          (row stride 72 u16 = 144 B, 16B-aligned for ds_read_b128).
// Phase B: 8 waves x 2 m-tiles; per matrix: B-frags = global b128 loads of the
//          k0-transposed weights (L1-hot), 8 MFMAs, pair-pack -> per-wave strip,
//          fully-coalesced 256B stores of q/k/v.
// NOTE: q is pre-scaled by 0.25*log2(e) so k2's softmax exp2 needs no multiply.
__global__ __launch_bounds__(512, 4) void k1_qkv(
    const float* __restrict__ x, const float* __restrict__ g1, const float* __restrict__ b1,
    const u16* __restrict__ wt,
    float* __restrict__ t_out, u32* __restrict__ qo, u32* __restrict__ ko, u32* __restrict__ vo)
{
    __shared__ u16 ys[256*72];           // [tok][72 u16]: 64 ch + 8 pad
    __shared__ u32 strip[8][16*34];      // per-wave 16 rows x (32 u32 + 2 pad)
    __shared__ float g_s[64], b_s[64];
    const int tid = threadIdx.x;
    if (tid < 64){ g_s[tid]=g1[tid]; b_s[tid]=b1[tid]; }

    const int p = blockIdx.x;
    const int bi = p >> 8, ph = (p >> 4) & 15, pw = p & 15;

    // ---- Phase A ----
    const int tok = tid >> 1, h = tid & 1;
    const int ti = tok >> 4, tj = tok & 15;
    const int r = ph*STP + ti, c = pw*STP + tj;
    const float* xb = x + ((size_t)bi*64 + 32*h)*HWIMG + (size_t)r*WW + c;
    const size_t gtokA = (size_t)p*TOK + tok;
    float* tp = t_out + gtokA*64 + 32*h;

    float v32[32];
    float s1 = 0.f, s2 = 0.f;
    #pragma unroll
    for (int c8 = 0; c8 < 4; ++c8){
        #pragma unroll
        for (int u = 0; u < 8; ++u){
            const float vv = xb[(size_t)(c8*8+u)*HWIMG];
            v32[c8*8+u] = vv;
            s1 += vv; s2 += vv*vv;
        }
        ((float4*)tp)[c8*2]   = make_float4(v32[c8*8+0],v32[c8*8+1],v32[c8*8+2],v32[c8*8+3]);
        ((float4*)tp)[c8*2+1] = make_float4(v32[c8*8+4],v32[c8*8+5],v32[c8*8+6],v32[c8*8+7]);
    }
    s1 += __shfl_xor(s1, 1);
    s2 += __shfl_xor(s2, 1);
    const float mu = s1 * (1.f/64.f);
    const float var = s2 * (1.f/64.f) - mu*mu;
    const float rs = rsqrtf(var + 1e-5f);
    __syncthreads();                      // g_s ready
    u32* ysw = (u32*)ys;
    #pragma unroll
    for (int i2 = 0; i2 < 16; ++i2){
        const int kk = 32*h + 2*i2;
        const float a0 = (v32[2*i2]  -mu)*rs*g_s[kk]   + b_s[kk];
        const float a1 = (v32[2*i2+1]-mu)*rs*g_s[kk+1] + b_s[kk+1];
        ysw[tok*36 + 16*h + i2] = pack2(a0, a1);
    }
    __syncthreads();                      // ys ready

    // ---- Phase B ----
    const int lane = tid & 63;
    const int w8   = tid >> 6;           // wave 0..7
    const int c15  = lane & 15;
    const int quad = lane >> 4;
    u32* stw = strip[w8];
    const size_t ptok = (size_t)p * TOK;

    for (int mt = 0; mt < 2; ++mt){
        const int T = w8*32 + mt*16;     // m-tile token base
        short8 af[2];
        #pragma unroll
        for (int kb = 0; kb < 2; ++kb)
            af[kb] = *(const short8*)(ys + (T + c15)*72 + kb*32 + quad*8);

        #pragma unroll
        for (int m = 0; m < 3; ++m){
            // B-frags for this matrix (b128 loads, L1/L2-hot)
            short8 bf[2][4];
            #pragma unroll
            for (int kb = 0; kb < 2; ++kb)
                #pragma unroll
                for (int nt = 0; nt < 4; ++nt)
                    bf[kb][nt] = *(const short8*)(wt + m*4096 + (nt*16 + c15)*64 + kb*32 + quad*8);

            f32x4 C[4];
            #pragma unroll
            for (int nt = 0; nt < 4; ++nt) C[nt] = (f32x4){0.f,0.f,0.f,0.f};
            #pragma unroll
            for (int kb = 0; kb < 2; ++kb)
                #pragma unroll
                for (int nt = 0; nt < 4; ++nt)
                    C[nt] = __builtin_amdgcn_mfma_f32_16x16x32_bf16(af[kb], bf[kb][nt], C[nt], 0, 0, 0);

            // fold softmax scale (dh^-0.5 * log2e) into q
            if (m == 0){
                #pragma unroll
                for (int nt = 0; nt < 4; ++nt)
                    #pragma unroll
                    for (int rr = 0; rr < 4; ++rr)
                        C[nt][rr] *= 0.3606737602222409f;
            }

            // pair-pack C tiles -> strip (b32 writes, <=2-way banks)
            #pragma unroll
            for (int nt = 0; nt < 4; ++nt){
                #pragma unroll
                for (int r2 = 0; r2 < 2; ++r2){
                    const float pv0 = __shfl_xor(C[nt][2*r2],   1);
                    const float pv1 = __shfl_xor(C[nt][2*r2+1], 1);
                    u32 wrd; int row;
                    if ((lane & 1) == 0){ wrd = pack2(C[nt][2*r2], pv0);  row = quad*4 + 2*r2; }
                    else                { wrd = pack2(pv1, C[nt][2*r2+1]); row = quad*4 + 2*r2 + 1; }
                    stw[row*34 + nt*8 + (c15 >> 1)] = wrd;
                }
            }

            // coalesced store: 8 insts x 64 lanes x 4B = 16 token rows
            u32* om = (m==0 ? qo : (m==1 ? ko : vo));
            #pragma unroll
            for (int i = 0; i < 8; ++i){
                const int flat = i*64 + lane;
                const u32 wv = stw[(flat >> 5)*34 + (flat & 31)];
                om[(ptok + T)*32 + flat] = wv;
            }
        }
    }
}

// ---------------- K2: MFMA attention (swapped QK^T), 2 blocks/patch, wave = head ----------------
// S^T = mfma(K, Q): col = q-token (lane&15) -> each lane owns one full q-row of P.
// P->LDS pack is pure in-lane cvt_pk (no shuffles); row-sum is in-lane + 2 shfl_xor.
// K and V frags RESIDENT in VGPRs. Grid split 2x over q-tiles -> 4 blocks/CU occupancy.
__global__ __launch_bounds__(256, 2) void k2_attn(
    const u16* __restrict__ qg, const u16* __restrict__ kg,
    const u16* __restrict__ vg, u16* __restrict__ og)   // og aliases qg
{
    __shared__ u16 plds[4][16*280];      // per-wave 16 q-rows x 280 u16 (560B stride)
    const int tid  = threadIdx.x;
    const int lane = tid & 63;
    const int h    = tid >> 6;           // wave = head
    const int pb   = blockIdx.x;
    const int p    = pb >> 1;            // patch
    const int half = pb & 1;             // q-tile half (0: qt 0-7, 1: qt 8-15)
    const int c15  = lane & 15;
    const int quad = lane >> 4;
    const size_t pbase = (size_t)p * TOK * 64;   // u16 elements

    // K A-frags resident (16 tiles; quads 2,3 = K-dim zero pad)
    short8 kf[16];
    #pragma unroll
    for (int t = 0; t < 16; ++t){
        short8 bf = {0,0,0,0,0,0,0,0};
        if (quad < 2)
            bf = *(const short8*)(kg + pbase + (size_t)(t*16 + c15)*64 + h*16 + quad*8);
        kf[t] = bf;
    }
    // V B-frags resident: vf[kb][j] = V[kb*32+quad*8+j][h*16+c15]
    short8 vf[8];
    #pragma unroll
    for (int kb = 0; kb < 8; ++kb){
        #pragma unroll
        for (int j = 0; j < 8; ++j)
            vf[kb][j] = (short)vg[pbase + (size_t)(kb*32 + quad*8 + j)*64 + h*16 + c15];
    }
    u16* pw  = &plds[h][0];
    u32* pwq = (u32*)pw + c15*140;       // this lane's q-row base (word units)

    for (int qi = 0; qi < 8; ++qi){
        const int qt = half*8 + qi;

        // Q B-frag (quads 2,3 are the K-pad -> zero); q pre-scaled in k1
        short8 qf = {0,0,0,0,0,0,0,0};
        if (quad < 2)
            qf = *(const short8*)(qg + pbase + (size_t)(qt*16 + c15)*64 + h*16 + quad*8);

        // S^T = K . Q^T : 16 k-tiles; lane holds P^T[k=t*16+quad*4+r][q=c15]
        f32x4 St[16];
        #pragma unroll
        for (int t = 0; t < 16; ++t){
            f32x4 z = {0.f,0.f,0.f,0.f};
            St[t] = __builtin_amdgcn_mfma_f32_16x16x32_bf16(kf[t], qf, z, 0, 0, 0);
        }

        // exp2 (scale folded into q); in-lane partial row sums
        float rsm[4] = {0.f,0.f,0.f,0.f};
        #pragma unroll
        for (int t = 0; t < 16; ++t){
            #pragma unroll
            for (int r = 0; r < 4; ++r){
                const float pe = fexp2(St[t][r]);
                St[t][r] = pe;
                rsm[r] += pe;
            }
        }
        float s = (rsm[0]+rsm[1]) + (rsm[2]+rsm[3]);
        s += __shfl_xor(s, 16);
        s += __shfl_xor(s, 32);
        const float rinv = __builtin_amdgcn_rcpf(s);
        float rv[4];
        #pragma unroll
        for (int r = 0; r < 4; ++r) rv[r] = __shfl(rinv, quad*4 + r);   // rinv for q-row quad*4+r

        // P -> LDS (bf16, unnormalized): adjacent k pairs are in-lane -> pure cvt_pk + b64 write
        #pragma unroll
        for (int t = 0; t < 16; ++t){
            uint2 wr;
            wr.x = pack2(St[t][0], St[t][1]);
            wr.y = pack2(St[t][2], St[t][3]);
            *(uint2*)(pwq + t*8 + quad*2) = wr;    // row c15, k-offset t*16+quad*4
        }

        // PV: O[q][d], A = P from LDS, B = resident V frags; two chains for ILP
        f32x4 O0 = {0.f,0.f,0.f,0.f}, O1 = {0.f,0.f,0.f,0.f};
        #pragma unroll
        for (int kb = 0; kb < 4; ++kb){
            const short8 a0 = *(const short8*)(pw + c15*280 + (2*kb)*32 + quad*8);
            const short8 a1 = *(const short8*)(pw + c15*280 + (2*kb+1)*32 + quad*8);
            O0 = __builtin_amdgcn_mfma_f32_16x16x32_bf16(a0, vf[2*kb],   O0, 0, 0, 0);
            O1 = __builtin_amdgcn_mfma_f32_16x16x32_bf16(a1, vf[2*kb+1], O1, 0, 0, 0);
        }

        // normalize rows by softmax sum (rcp) and store
        #pragma unroll
        for (int r = 0; r < 4; ++r){
            const float ov = (O0[r] + O1[r]) * rv[r];
            og[pbase + (size_t)(qt*16 + quad*4 + r)*64 + h*16 + c15] = f2bf(ov);
        }
    }
}

// ---------------- K3: MFMA proj + residual + LN2 + fc1 + GELU ----------------
__global__ __launch_bounds__(256, 2) void k3_proj_fc1(
    const u16* __restrict__ og, float* __restrict__ t,
    const float* __restrict__ wp, const float* __restrict__ bp,
    const float* __restrict__ g2, const float* __restrict__ b2,
    const float* __restrict__ wf1, const float* __restrict__ bf1,
    u32* __restrict__ y3)
{
    __shared__ u16 strip[4][16*136];     // per-wave: 16 rows x 136 u16 (272B stride)
    __shared__ float bp_s[64], g_s[64], b_s[64], bf_s[128];
    const int tid  = threadIdx.x;
    const int lane = tid & 63;
    const int w    = tid >> 6;
    const int c15  = lane & 15;
    const int quad = lane >> 4;
    if (tid < 64){ bp_s[tid]=bp[tid]; g_s[tid]=g2[tid]; b_s[tid]=b2[tid]; }
    else if (tid >= 128){ const int j = tid - 128; bf_s[j] = bf1[j]; }
    __syncthreads();

    // resident B-frags (bf16): wp 2kb x 4nt, wf1 2kb x 8nt
    short8 wpf[2][4];
    short8 wff[2][8];
    #pragma unroll
    for (int kb = 0; kb < 2; ++kb){
        #pragma unroll
        for (int nt = 0; nt < 4; ++nt){
            #pragma unroll
            for (int j = 0; j < 8; ++j)
                wpf[kb][nt][j] = (short)f2bf(wp[(kb*32 + quad*8 + j)*64 + nt*16 + c15]);
        }
        #pragma unroll
        for (int nt = 0; nt < 8; ++nt){
            #pragma unroll
            for (int j = 0; j < 8; ++j)
                wff[kb][nt][j] = (short)f2bf(wf1[(kb*32 + quad*8 + j)*128 + nt*16 + c15]);
        }
    }

    const int p = blockIdx.x;
    const size_t pbase = (size_t)p * TOK;           // token index base
    u16* st = strip[w];
    u32* stw = (u32*)st;

    const float gch[4] = { g_s[0*16+c15], g_s[1*16+c15], g_s[2*16+c15], g_s[3*16+c15] };
    const float bch[4] = { b_s[0*16+c15], b_s[1*16+c15], b_s[2*16+c15], b_s[3*16+c15] };
    const float bpc[4] = { bp_s[0*16+c15], bp_s[1*16+c15], bp_s[2*16+c15], bp_s[3*16+c15] };

    for (int rt = 0; rt < 4; ++rt){
        const int T = w*64 + rt*16;                 // m-tile token base

        // proj A-frags
        short8 af[2];
        #pragma unroll
        for (int kb = 0; kb < 2; ++kb)
            af[kb] = *(const short8*)(og + (pbase + T + c15)*64 + kb*32 + quad*8);

        // proj MFMA (bias init)
        f32x4 C[4];
        #pragma unroll
        for (int nt = 0; nt < 4; ++nt){
            const float b = bpc[nt];
            C[nt] = (f32x4){b, b, b, b};
        }
        #pragma unroll
        for (int kb = 0; kb < 2; ++kb)
            #pragma unroll
            for (int nt = 0; nt < 4; ++nt)
                C[nt] = __builtin_amdgcn_mfma_f32_16x16x32_bf16(af[kb], wpf[kb][nt], C[nt], 0, 0, 0);

        // residual add + t2 store (64B segments)
        #pragma unroll
        for (int nt = 0; nt < 4; ++nt){
            #pragma unroll
            for (int r = 0; r < 4; ++r)
                C[nt][r] += t[(pbase + T + quad*4 + r)*64 + nt*16 + c15];
        }
        #pragma unroll
        for (int nt = 0; nt < 4; ++nt){
            #pragma unroll
            for (int r = 0; r < 4; ++r)
                t[(pbase + T + quad*4 + r)*64 + nt*16 + c15] = C[nt][r];
        }

        // LN2 row stats (row = quad*4 + r)
        float rs1[4] = {0,0,0,0}, rs2[4] = {0,0,0,0};
        #pragma unroll
        for (int nt = 0; nt < 4; ++nt)
            #pragma unroll
            for (int r = 0; r < 4; ++r){ rs1[r] += C[nt][r]; rs2[r] += C[nt][r]*C[nt][r]; }
        #pragma unroll
        for (int r = 0; r < 4; ++r){
            rs1[r] += __shfl_xor(rs1[r], 1); rs2[r] += __shfl_xor(rs2[r], 1);
            rs1[r] += __shfl_xor(rs1[r], 2); rs2[r] += __shfl_xor(rs2[r], 2);
            rs1[r] += __shfl_xor(rs1[r], 4); rs2[r] += __shfl_xor(rs2[r], 4);
            rs1[r] += __shfl_xor(rs1[r], 8); rs2[r] += __shfl_xor(rs2[r], 8);
        }
        float muv[4], rsg[4];
        #pragma unroll
        for (int r = 0; r < 4; ++r){
            muv[r] = rs1[r]*(1.f/64.f);
            const float var = rs2[r]*(1.f/64.f) - muv[r]*muv[r];
            rsg[r] = rsqrtf(var + 1e-5f);
        }

        // normalized y -> strip (bf16, pair-packed b32 writes)
        #pragma unroll
        for (int nt = 0; nt < 4; ++nt){
            float yv[4];
            #pragma unroll
            for (int r = 0; r < 4; ++r)
                yv[r] = (C[nt][r]-muv[r])*rsg[r]*gch[nt] + bch[nt];
            #pragma unroll
            for (int r2 = 0; r2 < 2; ++r2){
                const float pv0 = __shfl_xor(yv[2*r2],   1);
                const float pv1 = __shfl_xor(yv[2*r2+1], 1);
                u32 wrd; int row;
                if ((lane & 1) == 0){ wrd = pack2(yv[2*r2], pv0);  row = quad*4 + 2*r2; }
                else                { wrd = pack2(pv1, yv[2*r2+1]); row = quad*4 + 2*r2 + 1; }
                *(u32*)(st + row*136 + nt*16 + (c15 & ~1)) = wrd;
            }
        }

        // fc1 A-frags from strip
        short8 pa[2];
        #pragma unroll
        for (int kb = 0; kb < 2; ++kb)
            pa[kb] = *(const short8*)(st + c15*136 + kb*32 + quad*8);

        // fc1 MFMA (bias init)
        f32x4 F[8];
        #pragma unroll
        for (int nt = 0; nt < 8; ++nt){
            const float b = bf_s[nt*16 + c15];
            F[nt] = (f32x4){b, b, b, b};
        }
        #pragma unroll
        for (int kb = 0; kb < 2; ++kb)
            #pragma unroll
            for (int nt = 0; nt < 8; ++nt)
                F[nt] = __builtin_amdgcn_mfma_f32_16x16x32_bf16(pa[kb], wff[kb][nt], F[nt], 0, 0, 0);

        // GELU
        #pragma unroll
        for (int nt = 0; nt < 8; ++nt)
            #pragma unroll
            for (int r = 0; r < 4; ++r)
                F[nt][r] = gelu_f(F[nt][r]);

        // y3 tile -> strip (pair-packed bf16)
        #pragma unroll
        for (int nt = 0; nt < 8; ++nt){
            #pragma unroll
            for (int r2 = 0; r2 < 2; ++r2){
                const float pv0 = __shfl_xor(F[nt][2*r2],   1);
                const float pv1 = __shfl_xor(F[nt][2*r2+1], 1);
                u32 wrd; int row;
                if ((lane & 1) == 0){ wrd = pack2(F[nt][2*r2], pv0);  row = quad*4 + 2*r2; }
                else                { wrd = pack2(pv1, F[nt][2*r2+1]); row = quad*4 + 2*r2 + 1; }
                *(u32*)(st + row*136 + nt*16 + (c15 & ~1)) = wrd;
            }
        }
        // coalesced y3 store: inst i covers token T+i, 64 u32 = 256B contiguous
        #pragma unroll
        for (int i = 0; i < 16; ++i){
            const u32 wv = stw[i*68 + lane];
            y3[(pbase + T + i)*64 + lane] = wv;
        }
    }
}

// ---------------- K4a: depthwise 5x5 conv + GELU + add (in-place on y3) ----------------
__global__ __launch_bounds__(256, 2) void k4a_dwconv(
    u32* y3, const float* __restrict__ wdw, const float* __restrict__ bdw)
{
    __shared__ u32 ys[400*33];       // 20x20 zero halo, 64 ch (32 words) + 1 pad
    __shared__ float wdwT[25*64];
    __shared__ float bdw_s[64];
    const int tid = threadIdx.x;
    const int p = blockIdx.x;
    const int ti = tid >> 4, tj = tid & 15;
    const int stok = (ti+2)*20 + (tj+2);
    const size_t gtok = (size_t)p*TOK + tid;
    for (int i = tid; i < 13200; i += 256) ys[i] = 0u;
    for (int half = 0; half < 2; ++half){
        __syncthreads();   // protect zero-init / previous phase reads
        for (int i = tid; i < 1600; i += 256){
            int chh = i/25, tap = i%25;
            wdwT[tap*64+chh] = wdw[(half*64+chh)*25 + tap];
        }
        if (tid < 64) bdw_s[tid] = bdw[half*64+tid];
        {
            const uint4* gp = (const uint4*)(y3 + gtok*64 + half*32);
            #pragma unroll
            for (int w = 0; w < 8; ++w){
                uint4 rr = gp[w];
                ys[stok*33 + w*4+0]=rr.x; ys[stok*33 + w*4+1]=rr.y;
                ys[stok*33 + w*4+2]=rr.z; ys[stok*33 + w*4+3]=rr.w;
            }
        }
        __syncthreads();
        const int base = stok*33;
        for (int ch2 = 0; ch2 < 32; ++ch2){
            float a0 = bdw_s[2*ch2], a1 = bdw_s[2*ch2+1];
            #pragma unroll
            for (int tap = 0; tap < 25; ++tap){
                const int di = tap/5, dj = tap%5;
                const int woff = ((di-2)*20 + (dj-2))*33;
                const u32 w0 = ys[base + woff + ch2];
                a0 += lo16(w0)*wdwT[tap*64+2*ch2];
                a1 += hi16(w0)*wdwT[tap*64+2*ch2+1];
            }
            const u32 own = ys[base + ch2];
            const float o0 = lo16(own) + gelu_f(a0);
            const float o1 = hi16(own) + gelu_f(a1);
            y3[gtok*64 + half*32 + ch2] = pack2(o0, o1);
        }
    }
}

// ---------------- K4b: MFMA fc2 + residual -> t3 [patch][ch][tok] ----------------
// 128->64 GEMM per token. wf2 resident as bf16 B-frags (no LDS, no spills);
// y3 rows load directly as A-frags (channel-major bf16, K=128 = 4 kb blocks).
__global__ __launch_bounds__(256, 2) void k4b_fc2(
    const u16* __restrict__ y3h, const float* __restrict__ t2,
    const float* __restrict__ wf2, const float* __restrict__ bf2,
    float* __restrict__ t3)
{
    const int tid  = threadIdx.x;
    const int lane = tid & 63;
    const int w    = tid >> 6;
    const int c15  = lane & 15;
    const int quad = lane >> 4;

    // resident B-frags: wf2 [128][64] fp32 -> bf16; kb over K=128, nt over N=64
    short8 wf[4][4];
    #pragma unroll
    for (int kb = 0; kb < 4; ++kb)
        #pragma unroll
        for (int nt = 0; nt < 4; ++nt)
            #pragma unroll
            for (int j = 0; j < 8; ++j)
                wf[kb][nt][j] = (short)f2bf(wf2[(kb*32 + quad*8 + j)*64 + nt*16 + c15]);

    float bcc[4];
    #pragma unroll
    for (int nt = 0; nt < 4; ++nt) bcc[nt] = bf2[nt*16 + c15];

    const int p = blockIdx.x;
    const size_t pbase = (size_t)p * TOK;
    float* t3p = t3 + (size_t)p * 16384;

    for (int rt = 0; rt < 4; ++rt){
        const int T = w*64 + rt*16;                // m-tile token base

        // A-frags: token rows of y3 (128 bf16 channels contiguous)
        short8 af[4];
        #pragma unroll
        for (int kb = 0; kb < 4; ++kb)
            af[kb] = *(const short8*)(y3h + (pbase + T + c15)*128 + kb*32 + quad*8);

        // MFMA with bias init
        f32x4 C[4];
        #pragma unroll
        for (int nt = 0; nt < 4; ++nt){
            const float b = bcc[nt];
            C[nt] = (f32x4){b, b, b, b};
        }
        #pragma unroll
        for (int kb = 0; kb < 4; ++kb)
            #pragma unroll
            for (int nt = 0; nt < 4; ++nt)
                C[nt] = __builtin_amdgcn_mfma_f32_16x16x32_bf16(af[kb], wf[kb][nt], C[nt], 0, 0, 0);

        // residual add (t2 fp32, token-major)
        #pragma unroll
        for (int nt = 0; nt < 4; ++nt)
            #pragma unroll
            for (int r = 0; r < 4; ++r)
                C[nt][r] += t2[(pbase + T + quad*4 + r)*64 + nt*16 + c15];

        // store t3 [ch][tok]: per (nt,r) inst, 16 chans x 16B chunks; 4 r-insts
        // tile each channel's 64B token line -> merged in write-back L2
        #pragma unroll
        for (int nt = 0; nt < 4; ++nt)
            #pragma unroll
            for (int r = 0; r < 4; ++r)
                t3p[(nt*16 + c15)*256 + T + quad*4 + r] = C[nt][r];
    }
}

// ---------------- K5: overlap-add gather + averaging ----------------
__global__ __launch_bounds__(256, 4) void k5_reverse(
    const float* __restrict__ t3, float* __restrict__ out)
{
    const int e = blockIdx.x*256 + threadIdx.x;
    if (e >= OUT_ELEMS) return;
    const int c = e % WW;
    int tmp = e / WW;
    const int r = tmp % HH;
    tmp /= HH;
    const int ch = tmp & 63;
    const int b = tmp >> 6;
    int pr = r/14; if (pr > 15) pr = 15;
    int pc = c/14; if (pc > 15) pc = 15;
    const int ra = r - pr*14, ca = c - pc*14;
    const int rb = ra + 14, cb = ca + 14;
    const bool hr = (pr >= 1) && (rb < 16);
    const bool hc = (pc >= 1) && (cb < 16);
    #define T3IDX(PH,PC,I,J) (((((b*16+(PH))*16+(PC))*64 + ch) << 8) + (I)*16 + (J))
    float s = t3[T3IDX(pr,pc,ra,ca)];
    if (hr)       s += t3[T3IDX(pr-1,pc,  rb,ca)];
    if (hc)       s += t3[T3IDX(pr,  pc-1,ra,cb)];
    if (hr && hc) s += t3[T3IDX(pr-1,pc-1,rb,cb)];
    const float f = (hr ? 0.5f : 1.f) * (hc ? 0.5f : 1.f);
    out[e] = s * f;
    #undef T3IDX
}

extern "C" void kernel_launch(void* const* d_in, const int* in_sizes, int n_in,
                              void* d_out, int out_size, void* d_ws, size_t ws_size,
                              hipStream_t stream)
{
    const float* x    = (const float*)d_in[0];
    const float* g1   = (const float*)d_in[1];
    const float* b1   = (const float*)d_in[2];
    const float* wq   = (const float*)d_in[3];
    const float* wk   = (const float*)d_in[4];
    const float* wv   = (const float*)d_in[5];
    const float* wp   = (const float*)d_in[6];
    const float* bp   = (const float*)d_in[7];
    const float* g2   = (const float*)d_in[8];
    const float* b2   = (const float*)d_in[9];
    const float* wf1  = (const float*)d_in[10];
    const float* bf1  = (const float*)d_in[11];
    const float* wdw  = (const float*)d_in[12];
    const float* bdw  = (const float*)d_in[13];
    const float* wf2  = (const float*)d_in[14];
    const float* bf2  = (const float*)d_in[15];

    char* ws = (char*)d_ws;
    // layout (bytes):
    //   [0,        33554432)  t   fp32  (becomes t2 in-place in k3)
    //   [33554432, 50331648)  q   bf16  (k2 output o overwrites it)
    //   [50331648, 67108864)  k   bf16  \  t3 fp32 aliases k+v after k2
    //   [67108864, 83886080)  v   bf16  /
    //   [83886080, 117440512) y3  bf16  (128/token; k4a updates in place)
    // wt (transposed bf16 qkv weights, 24 KB) lives at the head of d_out —
    // consumed by k1, fully overwritten by k5 at the end.
    float* t  = (float*)(ws);
    u32* q    = (u32*)(ws + 33554432);
    u32* k    = (u32*)(ws + 50331648);
    u32* v    = (u32*)(ws + 67108864);
    float* t3 = (float*)(ws + 50331648);
    u32* y3   = (u32*)(ws + 83886080);
    u16* wt   = (u16*)d_out;
    float* out = (float*)d_out;

    k0_wt      <<<48,        256, 0, stream>>>(wq, wk, wv, wt);
    k1_qkv     <<<NPATCH,    512, 0, stream>>>(x, g1, b1, wt, t, q, k, v);
    k2_attn    <<<NPATCH*2,  256, 0, stream>>>((const u16*)q, (const u16*)k, (const u16*)v, (u16*)q);
    k3_proj_fc1<<<NPATCH,    256, 0, stream>>>((const u16*)q, t, wp, bp, g2, b2, wf1, bf1, y3);
    k4a_dwconv <<<NPATCH,    256, 0, stream>>>(y3, wdw, bdw);
    k4b_fc2    <<<NPATCH,    256, 0, stream>>>((const u16*)y3, t, wf2, bf2, t3);
    k5_reverse <<<25538,     256, 0, stream>>>(t3, out);
}

// Round 4
// 313.128 us; speedup vs baseline: 1.3930x; 1.1137x over previous
//
#include <hip/hip_runtime.h>
#include <hip/hip_bf16.h>
#include <math.h>

#define HH 226
#define WW 226
#define HWIMG (226*226)
#define PS 16
#define STP 14
#define TOK 256
#define NPATCH 512
#define NTOK (NPATCH*TOK)
#define OUT_ELEMS (2*64*226*226)

typedef unsigned int u32;
typedef unsigned short u16;
typedef __attribute__((ext_vector_type(8))) short short8;
typedef __attribute__((ext_vector_type(4))) float f32x4;

__device__ __forceinline__ float lo16(u32 u){ return __uint_as_float(u << 16); }
__device__ __forceinline__ float hi16(u32 u){ return __uint_as_float(u & 0xFFFF0000u); }
__device__ __forceinline__ u16 f2bf(float f){
    u32 u = __float_as_uint(f);
    u += 0x7FFFu + ((u >> 16) & 1u);
    return (u16)(u >> 16);
}
__device__ __forceinline__ u32 pack2(float a, float b){
#if defined(__gfx950__) && __has_builtin(__builtin_amdgcn_cvt_pk_bf16_f32)
    auto r = __builtin_amdgcn_cvt_pk_bf16_f32(a, b);   // v_cvt_pk_bf16_f32 (RNE)
    return *(u32*)&r;
#else
    return (u32)f2bf(a) | ((u32)f2bf(b) << 16);
#endif
}
__device__ __forceinline__ float fexp2(float x){
#if __has_builtin(__builtin_amdgcn_exp2f)
    return __builtin_amdgcn_exp2f(x);                  // single v_exp_f32
#else
    return exp2f(x);
#endif
}
__device__ __forceinline__ void unpack8(uint4 r, float* d){
    d[0]=lo16(r.x); d[1]=hi16(r.x); d[2]=lo16(r.y); d[3]=hi16(r.y);
    d[4]=lo16(r.z); d[5]=hi16(r.z); d[6]=lo16(r.w); d[7]=hi16(r.w);
}
__device__ __forceinline__ uint4 pack8(const float* a){
    uint4 uu;
    uu.x = pack2(a[0], a[1]);
    uu.y = pack2(a[2], a[3]);
    uu.z = pack2(a[4], a[5]);
    uu.w = pack2(a[6], a[7]);
    return uu;
}
__device__ __forceinline__ float gelu_f(float x){
    return 0.5f * x * (1.0f + erff(x * 0.70710678118654752f));
}

template<int N>
__device__ __forceinline__ void store_bf16(u32* dst, const float* a){
    uint4* p4 = (uint4*)(dst);
    #pragma unroll
    for (int w4 = 0; w4 < N/8; ++w4) p4[w4] = pack8(a + 8*w4);
}

// ---------------- K0: transpose wq/wk/wv -> bf16 [n][k] (B-frag friendly) ----------------
__global__ __launch_bounds__(256, 4) void k0_wt(
    const float* __restrict__ wq, const float* __restrict__ wk,
    const float* __restrict__ wv, u16* __restrict__ wt)
{
    const int i = blockIdx.x*256 + threadIdx.x;     // 48 blocks * 256 = 12288
    const int m = i >> 12, rem = i & 4095;
    const int kk = rem >> 6, n = rem & 63;          // consecutive tid -> consecutive n (coalesced read)
    const float* w = (m==0 ? wq : (m==1 ? wk : wv));
    wt[m*4096 + n*64 + kk] = f2bf(w[kk*64 + n]);
}

// ---------------- K1: patch gather + LN1 (LDS) + MFMA QKV ----------------
// Phase A: 2 threads/token gather x, LN1 via pair-shuffle, normalized bf16 -> ys
//          (row stride 72 u16 = 144 B, 16B-aligned for ds_read_b128).
// Phase B: 8 waves x 2 m-tiles; per matrix: B-frags = global b128 loads of the
//          k0-transposed weights (L1-hot), 8 MFMAs, pair-pack -> per-wave strip,
//          fully-coalesced 256B stores of q/k/v.
// NOTE: q is pre-scaled by 0.25*log2(e) so k2's softmax exp2 needs no multiply.
__global__ __launch_bounds__(512, 4) void k1_qkv(
    const float* __restrict__ x, const float* __restrict__ g1, const float* __restrict__ b1,
    const u16* __restrict__ wt,
    float* __restrict__ t_out, u32* __restrict__ qo, u32* __restrict__ ko, u32* __restrict__ vo)
{
    __shared__ u16 ys[256*72];           // [tok][72 u16]: 64 ch + 8 pad
    __shared__ u32 strip[8][16*34];      // per-wave 16 rows x (32 u32 + 2 pad)
    __shared__ float g_s[64], b_s[64];
    const int tid = threadIdx.x;
    if (tid < 64){ g_s[tid]=g1[tid]; b_s[tid]=b1[tid]; }

    const int p = blockIdx.x;
    const int bi = p >> 8, ph = (p >> 4) & 15, pw = p & 15;

    // ---- Phase A ----
    const int tok = tid >> 1, h = tid & 1;
    const int ti = tok >> 4, tj = tok & 15;
    const int r = ph*STP + ti, c = pw*STP + tj;
    const float* xb = x + ((size_t)bi*64 + 32*h)*HWIMG + (size_t)r*WW + c;
    const size_t gtokA = (size_t)p*TOK + tok;
    float* tp = t_out + gtokA*64 + 32*h;

    float v32[32];
    float s1 = 0.f, s2 = 0.f;
    #pragma unroll
    for (int c8 = 0; c8 < 4; ++c8){
        #pragma unroll
        for (int u = 0; u < 8; ++u){
            const float vv = xb[(size_t)(c8*8+u)*HWIMG];
            v32[c8*8+u] = vv;
            s1 += vv; s2 += vv*vv;
        }
        ((float4*)tp)[c8*2]   = make_float4(v32[c8*8+0],v32[c8*8+1],v32[c8*8+2],v32[c8*8+3]);
        ((float4*)tp)[c8*2+1] = make_float4(v32[c8*8+4],v32[c8*8+5],v32[c8*8+6],v32[c8*8+7]);
    }
    s1 += __shfl_xor(s1, 1);
    s2 += __shfl_xor(s2, 1);
    const float mu = s1 * (1.f/64.f);
    const float var = s2 * (1.f/64.f) - mu*mu;
    const float rs = rsqrtf(var + 1e-5f);
    __syncthreads();                      // g_s ready
    u32* ysw = (u32*)ys;
    #pragma unroll
    for (int i2 = 0; i2 < 16; ++i2){
        const int kk = 32*h + 2*i2;
        const float a0 = (v32[2*i2]  -mu)*rs*g_s[kk]   + b_s[kk];
        const float a1 = (v32[2*i2+1]-mu)*rs*g_s[kk+1] + b_s[kk+1];
        ysw[tok*36 + 16*h + i2] = pack2(a0, a1);
    }
    __syncthreads();                      // ys ready

    // ---- Phase B ----
    const int lane = tid & 63;
    const int w8   = tid >> 6;           // wave 0..7
    const int c15  = lane & 15;
    const int quad = lane >> 4;
    u32* stw = strip[w8];
    const size_t ptok = (size_t)p * TOK;

    for (int mt = 0; mt < 2; ++mt){
        const int T = w8*32 + mt*16;     // m-tile token base
        short8 af[2];
        #pragma unroll
        for (int kb = 0; kb < 2; ++kb)
            af[kb] = *(const short8*)(ys + (T + c15)*72 + kb*32 + quad*8);

        #pragma unroll
        for (int m = 0; m < 3; ++m){
            // B-frags for this matrix (b128 loads, L1/L2-hot)
            short8 bf[2][4];
            #pragma unroll
            for (int kb = 0; kb < 2; ++kb)
                #pragma unroll
                for (int nt = 0; nt < 4; ++nt)
                    bf[kb][nt] = *(const short8*)(wt + m*4096 + (nt*16 + c15)*64 + kb*32 + quad*8);

            f32x4 C[4];
            #pragma unroll
            for (int nt = 0; nt < 4; ++nt) C[nt] = (f32x4){0.f,0.f,0.f,0.f};
            #pragma unroll
            for (int kb = 0; kb < 2; ++kb)
                #pragma unroll
                for (int nt = 0; nt < 4; ++nt)
                    C[nt] = __builtin_amdgcn_mfma_f32_16x16x32_bf16(af[kb], bf[kb][nt], C[nt], 0, 0, 0);

            // fold softmax scale (dh^-0.5 * log2e) into q
            if (m == 0){
                #pragma unroll
                for (int nt = 0; nt < 4; ++nt)
                    #pragma unroll
                    for (int rr = 0; rr < 4; ++rr)
                        C[nt][rr] *= 0.3606737602222409f;
            }

            // pair-pack C tiles -> strip (b32 writes, <=2-way banks)
            #pragma unroll
            for (int nt = 0; nt < 4; ++nt){
                #pragma unroll
                for (int r2 = 0; r2 < 2; ++r2){
                    const float pv0 = __shfl_xor(C[nt][2*r2],   1);
                    const float pv1 = __shfl_xor(C[nt][2*r2+1], 1);
                    u32 wrd; int row;
                    if ((lane & 1) == 0){ wrd = pack2(C[nt][2*r2], pv0);  row = quad*4 + 2*r2; }
                    else                { wrd = pack2(pv1, C[nt][2*r2+1]); row = quad*4 + 2*r2 + 1; }
                    stw[row*34 + nt*8 + (c15 >> 1)] = wrd;
                }
            }

            // coalesced store: 8 insts x 64 lanes x 4B = 16 token rows
            u32* om = (m==0 ? qo : (m==1 ? ko : vo));
            #pragma unroll
            for (int i = 0; i < 8; ++i){
                const int flat = i*64 + lane;
                const u32 wv = stw[(flat >> 5)*34 + (flat & 31)];
                om[(ptok + T)*32 + flat] = wv;
            }
        }
    }
}

// ---------------- K2: MFMA attention (swapped QK^T), 2 blocks/patch, wave = head ----------------
// S^T = mfma(K, Q): col = q-token (lane&15) -> each lane owns one full q-row of P.
// P->LDS pack is pure in-lane cvt_pk (no shuffles); row-sum is in-lane + 2 shfl_xor.
// K and V frags RESIDENT in VGPRs. Grid split 2x over q-tiles -> 4 blocks/CU occupancy.
__global__ __launch_bounds__(256, 2) void k2_attn(
    const u16* __restrict__ qg, const u16* __restrict__ kg,
    const u16* __restrict__ vg, u16* __restrict__ og)   // og aliases qg
{
    __shared__ u16 plds[4][16*280];      // per-wave 16 q-rows x 280 u16 (560B stride)
    const int tid  = threadIdx.x;
    const int lane = tid & 63;
    const int h    = tid >> 6;           // wave = head
    const int pb   = blockIdx.x;
    const int p    = pb >> 1;            // patch
    const int half = pb & 1;             // q-tile half (0: qt 0-7, 1: qt 8-15)
    const int c15  = lane & 15;
    const int quad = lane >> 4;
    const size_t pbase = (size_t)p * TOK * 64;   // u16 elements

    // K A-frags resident (16 tiles; quads 2,3 = K-dim zero pad)
    short8 kf[16];
    #pragma unroll
    for (int t = 0; t < 16; ++t){
        short8 bf = {0,0,0,0,0,0,0,0};
        if (quad < 2)
            bf = *(const short8*)(kg + pbase + (size_t)(t*16 + c15)*64 + h*16 + quad*8);
        kf[t] = bf;
    }
    // V B-frags resident: vf[kb][j] = V[kb*32+quad*8+j][h*16+c15]
    short8 vf[8];
    #pragma unroll
    for (int kb = 0; kb < 8; ++kb){
        #pragma unroll
        for (int j = 0; j < 8; ++j)
            vf[kb][j] = (short)vg[pbase + (size_t)(kb*32 + quad*8 + j)*64 + h*16 + c15];
    }
    u16* pw  = &plds[h][0];
    u32* pwq = (u32*)pw + c15*140;       // this lane's q-row base (word units)

    for (int qi = 0; qi < 8; ++qi){
        const int qt = half*8 + qi;

        // Q B-frag (quads 2,3 are the K-pad -> zero); q pre-scaled in k1
        short8 qf = {0,0,0,0,0,0,0,0};
        if (quad < 2)
            qf = *(const short8*)(qg + pbase + (size_t)(qt*16 + c15)*64 + h*16 + quad*8);

        // S^T = K . Q^T : 16 k-tiles; lane holds P^T[k=t*16+quad*4+r][q=c15]
        f32x4 St[16];
        #pragma unroll
        for (int t = 0; t < 16; ++t){
            f32x4 z = {0.f,0.f,0.f,0.f};
            St[t] = __builtin_amdgcn_mfma_f32_16x16x32_bf16(kf[t], qf, z, 0, 0, 0);
        }

        // exp2 (scale folded into q); in-lane partial row sums
        float rsm[4] = {0.f,0.f,0.f,0.f};
        #pragma unroll
        for (int t = 0; t < 16; ++t){
            #pragma unroll
            for (int r = 0; r < 4; ++r){
                const float pe = fexp2(St[t][r]);
                St[t][r] = pe;
                rsm[r] += pe;
            }
        }
        float s = (rsm[0]+rsm[1]) + (rsm[2]+rsm[3]);
        s += __shfl_xor(s, 16);
        s += __shfl_xor(s, 32);
        const float rinv = __builtin_amdgcn_rcpf(s);
        float rv[4];
        #pragma unroll
        for (int r = 0; r < 4; ++r) rv[r] = __shfl(rinv, quad*4 + r);   // rinv for q-row quad*4+r

        // P -> LDS (bf16, unnormalized): adjacent k pairs are in-lane -> pure cvt_pk + b64 write
        #pragma unroll
        for (int t = 0; t < 16; ++t){
            uint2 wr;
            wr.x = pack2(St[t][0], St[t][1]);
            wr.y = pack2(St[t][2], St[t][3]);
            *(uint2*)(pwq + t*8 + quad*2) = wr;    // row c15, k-offset t*16+quad*4
        }

        // PV: O[q][d], A = P from LDS, B = resident V frags; two chains for ILP
        f32x4 O0 = {0.f,0.f,0.f,0.f}, O1 = {0.f,0.f,0.f,0.f};
        #pragma unroll
        for (int kb = 0; kb < 4; ++kb){
            const short8 a0 = *(const short8*)(pw + c15*280 + (2*kb)*32 + quad*8);
            const short8 a1 = *(const short8*)(pw + c15*280 + (2*kb+1)*32 + quad*8);
            O0 = __builtin_amdgcn_mfma_f32_16x16x32_bf16(a0, vf[2*kb],   O0, 0, 0, 0);
            O1 = __builtin_amdgcn_mfma_f32_16x16x32_bf16(a1, vf[2*kb+1], O1, 0, 0, 0);
        }

        // normalize rows by softmax sum (rcp) and store
        #pragma unroll
        for (int r = 0; r < 4; ++r){
            const float ov = (O0[r] + O1[r]) * rv[r];
            og[pbase + (size_t)(qt*16 + quad*4 + r)*64 + h*16 + c15] = f2bf(ov);
        }
    }
}

// ---------------- K3: MFMA proj + residual + LN2 + fc1 + GELU ----------------
__global__ __launch_bounds__(256, 2) void k3_proj_fc1(
    const u16* __restrict__ og, float* __restrict__ t,
    const float* __restrict__ wp, const float* __restrict__ bp,
    const float* __restrict__ g2, const float* __restrict__ b2,
    const float* __restrict__ wf1, const float* __restrict__ bf1,
    u32* __restrict__ y3)
{
    __shared__ u16 strip[4][16*136];     // per-wave: 16 rows x 136 u16 (272B stride)
    __shared__ float bp_s[64], g_s[64], b_s[64], bf_s[128];
    const int tid  = threadIdx.x;
    const int lane = tid & 63;
    const int w    = tid >> 6;
    const int c15  = lane & 15;
    const int quad = lane >> 4;
    if (tid < 64){ bp_s[tid]=bp[tid]; g_s[tid]=g2[tid]; b_s[tid]=b2[tid]; }
    else if (tid >= 128){ const int j = tid - 128; bf_s[j] = bf1[j]; }
    __syncthreads();

    // resident B-frags (bf16): wp 2kb x 4nt, wf1 2kb x 8nt
    short8 wpf[2][4];
    short8 wff[2][8];
    #pragma unroll
    for (int kb = 0; kb < 2; ++kb){
        #pragma unroll
        for (int nt = 0; nt < 4; ++nt){
            #pragma unroll
            for (int j = 0; j < 8; ++j)
                wpf[kb][nt][j] = (short)f2bf(wp[(kb*32 + quad*8 + j)*64 + nt*16 + c15]);
        }
        #pragma unroll
        for (int nt = 0; nt < 8; ++nt){
            #pragma unroll
            for (int j = 0; j < 8; ++j)
                wff[kb][nt][j] = (short)f2bf(wf1[(kb*32 + quad*8 + j)*128 + nt*16 + c15]);
        }
    }

    const int p = blockIdx.x;
    const size_t pbase = (size_t)p * TOK;           // token index base
    u16* st = strip[w];
    u32* stw = (u32*)st;

    const float gch[4] = { g_s[0*16+c15], g_s[1*16+c15], g_s[2*16+c15], g_s[3*16+c15] };
    const float bch[4] = { b_s[0*16+c15], b_s[1*16+c15], b_s[2*16+c15], b_s[3*16+c15] };
    const float bpc[4] = { bp_s[0*16+c15], bp_s[1*16+c15], bp_s[2*16+c15], bp_s[3*16+c15] };

    for (int rt = 0; rt < 4; ++rt){
        const int T = w*64 + rt*16;                 // m-tile token base

        // proj A-frags
        short8 af[2];
        #pragma unroll
        for (int kb = 0; kb < 2; ++kb)
            af[kb] = *(const short8*)(og + (pbase + T + c15)*64 + kb*32 + quad*8);

        // proj MFMA (bias init)
        f32x4 C[4];
        #pragma unroll
        for (int nt = 0; nt < 4; ++nt){
            const float b = bpc[nt];
            C[nt] = (f32x4){b, b, b, b};
        }
        #pragma unroll
        for (int kb = 0; kb < 2; ++kb)
            #pragma unroll
            for (int nt = 0; nt < 4; ++nt)
                C[nt] = __builtin_amdgcn_mfma_f32_16x16x32_bf16(af[kb], wpf[kb][nt], C[nt], 0, 0, 0);

        // residual add + t2 store (64B segments)
        #pragma unroll
        for (int nt = 0; nt < 4; ++nt){
            #pragma unroll
            for (int r = 0; r < 4; ++r)
                C[nt][r] += t[(pbase + T + quad*4 + r)*64 + nt*16 + c15];
        }
        #pragma unroll
        for (int nt = 0; nt < 4; ++nt){
            #pragma unroll
            for (int r = 0; r < 4; ++r)
                t[(pbase + T + quad*4 + r)*64 + nt*16 + c15] = C[nt][r];
        }

        // LN2 row stats (row = quad*4 + r)
        float rs1[4] = {0,0,0,0}, rs2[4] = {0,0,0,0};
        #pragma unroll
        for (int nt = 0; nt < 4; ++nt)
            #pragma unroll
            for (int r = 0; r < 4; ++r){ rs1[r] += C[nt][r]; rs2[r] += C[nt][r]*C[nt][r]; }
        #pragma unroll
        for (int r = 0; r < 4; ++r){
            rs1[r] += __shfl_xor(rs1[r], 1); rs2[r] += __shfl_xor(rs2[r], 1);
            rs1[r] += __shfl_xor(rs1[r], 2); rs2[r] += __shfl_xor(rs2[r], 2);
            rs1[r] += __shfl_xor(rs1[r], 4); rs2[r] += __shfl_xor(rs2[r], 4);
            rs1[r] += __shfl_xor(rs1[r], 8); rs2[r] += __shfl_xor(rs2[r], 8);
        }
        float muv[4], rsg[4];
        #pragma unroll
        for (int r = 0; r < 4; ++r){
            muv[r] = rs1[r]*(1.f/64.f);
            const float var = rs2[r]*(1.f/64.f) - muv[r]*muv[r];
            rsg[r] = rsqrtf(var + 1e-5f);
        }

        // normalized y -> strip (bf16, pair-packed b32 writes)
        #pragma unroll
        for (int nt = 0; nt < 4; ++nt){
            float yv[4];
            #pragma unroll
            for (int r = 0; r < 4; ++r)
                yv[r] = (C[nt][r]-muv[r])*rsg[r]*gch[nt] + bch[nt];
            #pragma unroll
            for (int r2 = 0; r2 < 2; ++r2){
                const float pv0 = __shfl_xor(yv[2*r2],   1);
                const float pv1 = __shfl_xor(yv[2*r2+1], 1);
                u32 wrd; int row;
                if ((lane & 1) == 0){ wrd = pack2(yv[2*r2], pv0);  row = quad*4 + 2*r2; }
                else                { wrd = pack2(pv1, yv[2*r2+1]); row = quad*4 + 2*r2 + 1; }
                *(u32*)(st + row*136 + nt*16 + (c15 & ~1)) = wrd;
            }
        }

        // fc1 A-frags from strip
        short8 pa[2];
        #pragma unroll
        for (int kb = 0; kb < 2; ++kb)
            pa[kb] = *(const short8*)(st + c15*136 + kb*32 + quad*8);

        // fc1 MFMA (bias init)
        f32x4 F[8];
        #pragma unroll
        for (int nt = 0; nt < 8; ++nt){
            const float b = bf_s[nt*16 + c15];
            F[nt] = (f32x4){b, b, b, b};
        }
        #pragma unroll
        for (int kb = 0; kb < 2; ++kb)
            #pragma unroll
            for (int nt = 0; nt < 8; ++nt)
                F[nt] = __builtin_amdgcn_mfma_f32_16x16x32_bf16(pa[kb], wff[kb][nt], F[nt], 0, 0, 0);

        // GELU
        #pragma unroll
        for (int nt = 0; nt < 8; ++nt)
            #pragma unroll
            for (int r = 0; r < 4; ++r)
                F[nt][r] = gelu_f(F[nt][r]);

        // y3 tile -> strip (pair-packed bf16)
        #pragma unroll
        for (int nt = 0; nt < 8; ++nt){
            #pragma unroll
            for (int r2 = 0; r2 < 2; ++r2){
                const float pv0 = __shfl_xor(F[nt][2*r2],   1);
                const float pv1 = __shfl_xor(F[nt][2*r2+1], 1);
                u32 wrd; int row;
                if ((lane & 1) == 0){ wrd = pack2(F[nt][2*r2], pv0);  row = quad*4 + 2*r2; }
                else                { wrd = pack2(pv1, F[nt][2*r2+1]); row = quad*4 + 2*r2 + 1; }
                *(u32*)(st + row*136 + nt*16 + (c15 & ~1)) = wrd;
            }
        }
        // coalesced y3 store: inst i covers token T+i, 64 u32 = 256B contiguous
        #pragma unroll
        for (int i = 0; i < 16; ++i){
            const u32 wv = stw[i*68 + lane];
            y3[(pbase + T + i)*64 + lane] = wv;
        }
    }
}

// ---------------- K4a: depthwise 5x5 conv + GELU + add (in-place on y3) ----------------
// thread = (column-group, channel-pair): weights in 50 regs (zero LDS weight reads),
// 5x5 sliding register window down each column (5 LDS reads/output, conflict-free:
// lanes 0..31 read consecutive ch2 words), natively coalesced 128B-segment stores.
__global__ __launch_bounds__(256, 2) void k4a_dwconv(
    u32* y3, const float* __restrict__ wdw, const float* __restrict__ bdw)
{
    __shared__ u32 ys[400*33];       // 20x20 zero halo, 32 u32 (one half) + 1 pad
    const int tid = threadIdx.x;
    const int p = blockIdx.x;
    const int ch2 = tid & 31;        // channel pair within the half
    const int cg  = tid >> 5;        // 0..7 -> image columns 2cg, 2cg+1
    const size_t ptok = (size_t)p * TOK;

    // token mapping for the fill phase (thread = token)
    const int fti = tid >> 4, ftj = tid & 15;
    const int fstok = (fti+2)*20 + (ftj+2);

    for (int i = tid; i < 13200; i += 256) ys[i] = 0u;

    for (int half = 0; half < 2; ++half){
        __syncthreads();             // zero-init done / previous half's readers done
        // fill halo interior: 32 words of this half per token (coalesced b128 reads)
        {
            const uint4* gp = (const uint4*)(y3 + (ptok + tid)*64 + half*32);
            #pragma unroll
            for (int w = 0; w < 8; ++w){
                uint4 rr = gp[w];
                ys[fstok*33 + w*4+0]=rr.x; ys[fstok*33 + w*4+1]=rr.y;
                ys[fstok*33 + w*4+2]=rr.z; ys[fstok*33 + w*4+3]=rr.w;
            }
        }
        // weights -> 50 regs (L1/L2-hot, 12.8KB total)
        float wA[25], wB[25];
        #pragma unroll
        for (int tap = 0; tap < 25; ++tap){
            wA[tap] = wdw[(half*64 + 2*ch2+0)*25 + tap];
            wB[tap] = wdw[(half*64 + 2*ch2+1)*25 + tap];
        }
        const float bA = bdw[half*64 + 2*ch2+0];
        const float bB = bdw[half*64 + 2*ch2+1];
        __syncthreads();             // ys ready

        #pragma unroll
        for (int cc = 0; cc < 2; ++cc){
            const int c  = cg*2 + cc;          // image column 0..15
            const int hc = c + 2;              // halo column of the center
            u32 win[5][5];                     // halo rows (mod 5) x 5 tap cols
            #pragma unroll
            for (int r = 0; r < 4; ++r)
                #pragma unroll
                for (int j = 0; j < 5; ++j)
                    win[r][j] = ys[(r*20 + hc-2+j)*33 + ch2];
            #pragma unroll
            for (int row = 0; row < 16; ++row){
                #pragma unroll
                for (int j = 0; j < 5; ++j)
                    win[(row+4)%5][j] = ys[((row+4)*20 + hc-2+j)*33 + ch2];
                float a0 = bA, a1 = bB;
                #pragma unroll
                for (int di = 0; di < 5; ++di){
                    #pragma unroll
                    for (int dj = 0; dj < 5; ++dj){
                        const u32 v = win[(row+di)%5][dj];
                        a0 += lo16(v)*wA[di*5+dj];
                        a1 += hi16(v)*wB[di*5+dj];
                    }
                }
                const u32 own = win[(row+2)%5][2];   // center pixel, free residual
                const float o0 = lo16(own) + gelu_f(a0);
                const float o1 = hi16(own) + gelu_f(a1);
                // coalesced: lanes 0..31 = ch2 0..31 -> one 128B segment per token
                y3[(ptok + row*16 + c)*64 + half*32 + ch2] = pack2(o0, o1);
            }
        }
    }
}

// ---------------- K4b: MFMA fc2 + residual -> t3 [patch][ch][tok] ----------------
// 128->64 GEMM per token. wf2 resident as bf16 B-frags (no LDS, no spills);
// y3 rows load directly as A-frags (channel-major bf16, K=128 = 4 kb blocks).
__global__ __launch_bounds__(256, 2) void k4b_fc2(
    const u16* __restrict__ y3h, const float* __restrict__ t2,
    const float* __restrict__ wf2, const float* __restrict__ bf2,
    float* __restrict__ t3)
{
    const int tid  = threadIdx.x;
    const int lane = tid & 63;
    const int w    = tid >> 6;
    const int c15  = lane & 15;
    const int quad = lane >> 4;

    // resident B-frags: wf2 [128][64] fp32 -> bf16; kb over K=128, nt over N=64
    short8 wf[4][4];
    #pragma unroll
    for (int kb = 0; kb < 4; ++kb)
        #pragma unroll
        for (int nt = 0; nt < 4; ++nt)
            #pragma unroll
            for (int j = 0; j < 8; ++j)
                wf[kb][nt][j] = (short)f2bf(wf2[(kb*32 + quad*8 + j)*64 + nt*16 + c15]);

    float bcc[4];
    #pragma unroll
    for (int nt = 0; nt < 4; ++nt) bcc[nt] = bf2[nt*16 + c15];

    const int p = blockIdx.x;
    const size_t pbase = (size_t)p * TOK;
    float* t3p = t3 + (size_t)p * 16384;

    for (int rt = 0; rt < 4; ++rt){
        const int T = w*64 + rt*16;                // m-tile token base

        // A-frags: token rows of y3 (128 bf16 channels contiguous)
        short8 af[4];
        #pragma unroll
        for (int kb = 0; kb < 4; ++kb)
            af[kb] = *(const short8*)(y3h + (pbase + T + c15)*128 + kb*32 + quad*8);

        // MFMA with bias init
        f32x4 C[4];
        #pragma unroll
        for (int nt = 0; nt < 4; ++nt){
            const float b = bcc[nt];
            C[nt] = (f32x4){b, b, b, b};
        }
        #pragma unroll
        for (int kb = 0; kb < 4; ++kb)
            #pragma unroll
            for (int nt = 0; nt < 4; ++nt)
                C[nt] = __builtin_amdgcn_mfma_f32_16x16x32_bf16(af[kb], wf[kb][nt], C[nt], 0, 0, 0);

        // residual add (t2 fp32, token-major)
        #pragma unroll
        for (int nt = 0; nt < 4; ++nt)
            #pragma unroll
            for (int r = 0; r < 4; ++r)
                C[nt][r] += t2[(pbase + T + quad*4 + r)*64 + nt*16 + c15];

        // store t3 [ch][tok]: per (nt,r) inst, 16 chans x 16B chunks; 4 r-insts
        // tile each channel's 64B token line -> merged in write-back L2
        #pragma unroll
        for (int nt = 0; nt < 4; ++nt)
            #pragma unroll
            for (int r = 0; r < 4; ++r)
                t3p[(nt*16 + c15)*256 + T + quad*4 + r] = C[nt][r];
    }
}

// ---------------- K5: overlap-add gather + averaging ----------------
__global__ __launch_bounds__(256, 4) void k5_reverse(
    const float* __restrict__ t3, float* __restrict__ out)
{
    const int e = blockIdx.x*256 + threadIdx.x;
    if (e >= OUT_ELEMS) return;
    const int c = e % WW;
    int tmp = e / WW;
    const int r = tmp % HH;
    tmp /= HH;
    const int ch = tmp & 63;
    const int b = tmp >> 6;
    int pr = r/14; if (pr > 15) pr = 15;
    int pc = c/14; if (pc > 15) pc = 15;
    const int ra = r - pr*14, ca = c - pc*14;
    const int rb = ra + 14, cb = ca + 14;
    const bool hr = (pr >= 1) && (rb < 16);
    const bool hc = (pc >= 1) && (cb < 16);
    #define T3IDX(PH,PC,I,J) (((((b*16+(PH))*16+(PC))*64 + ch) << 8) + (I)*16 + (J))
    float s = t3[T3IDX(pr,pc,ra,ca)];
    if (hr)       s += t3[T3IDX(pr-1,pc,  rb,ca)];
    if (hc)       s += t3[T3IDX(pr,  pc-1,ra,cb)];
    if (hr && hc) s += t3[T3IDX(pr-1,pc-1,rb,cb)];
    const float f = (hr ? 0.5f : 1.f) * (hc ? 0.5f : 1.f);
    out[e] = s * f;
    #undef T3IDX
}

extern "C" void kernel_launch(void* const* d_in, const int* in_sizes, int n_in,
                              void* d_out, int out_size, void* d_ws, size_t ws_size,
                              hipStream_t stream)
{
    const float* x    = (const float*)d_in[0];
    const float* g1   = (const float*)d_in[1];
    const float* b1   = (const float*)d_in[2];
    const float* wq   = (const float*)d_in[3];
    const float* wk   = (const float*)d_in[4];
    const float* wv   = (const float*)d_in[5];
    const float* wp   = (const float*)d_in[6];
    const float* bp   = (const float*)d_in[7];
    const float* g2   = (const float*)d_in[8];
    const float* b2   = (const float*)d_in[9];
    const float* wf1  = (const float*)d_in[10];
    const float* bf1  = (const float*)d_in[11];
    const float* wdw  = (const float*)d_in[12];
    const float* bdw  = (const float*)d_in[13];
    const float* wf2  = (const float*)d_in[14];
    const float* bf2  = (const float*)d_in[15];

    char* ws = (char*)d_ws;
    // layout (bytes):
    //   [0,        33554432)  t   fp32  (becomes t2 in-place in k3)
    //   [33554432, 50331648)  q   bf16  (k2 output o overwrites it)
    //   [50331648, 67108864)  k   bf16  \  t3 fp32 aliases k+v after k2
    //   [67108864, 83886080)  v   bf16  /
    //   [83886080, 117440512) y3  bf16  (128/token; k4a updates in place)
    // wt (transposed bf16 qkv weights, 24 KB) lives at the head of d_out —
    // consumed by k1, fully overwritten by k5 at the end.
    float* t  = (float*)(ws);
    u32* q    = (u32*)(ws + 33554432);
    u32* k    = (u32*)(ws + 50331648);
    u32* v    = (u32*)(ws + 67108864);
    float* t3 = (float*)(ws + 50331648);
    u32* y3   = (u32*)(ws + 83886080);
    u16* wt   = (u16*)d_out;
    float* out = (float*)d_out;

    k0_wt      <<<48,        256, 0, stream>>>(wq, wk, wv, wt);
    k1_qkv     <<<NPATCH,    512, 0, stream>>>(x, g1, b1, wt, t, q, k, v);
    k2_attn    <<<NPATCH*2,  256, 0, stream>>>((const u16*)q, (const u16*)k, (const u16*)v, (u16*)q);
    k3_proj_fc1<<<NPATCH,    256, 0, stream>>>((const u16*)q, t, wp, bp, g2, b2, wf1, bf1, y3);
    k4a_dwconv <<<NPATCH,    256, 0, stream>>>(y3, wdw, bdw);
    k4b_fc2    <<<NPATCH,    256, 0, stream>>>((const u16*)y3, t, wf2, bf2, t3);
    k5_reverse <<<25538,     256, 0, stream>>>(t3, out);
}

// Round 5
// 303.192 us; speedup vs baseline: 1.4387x; 1.0328x over previous
//
#include <hip/hip_runtime.h>
#include <hip/hip_bf16.h>
#include <math.h>

#define HH 226
#define WW 226
#define HWIMG (226*226)
#define PS 16
#define STP 14
#define TOK 256
#define NPATCH 512
#define NTOK (NPATCH*TOK)
#define OUT_ELEMS (2*64*226*226)

typedef unsigned int u32;
typedef unsigned short u16;
typedef __attribute__((ext_vector_type(8))) short short8;
typedef __attribute__((ext_vector_type(4))) float f32x4;

__device__ __forceinline__ float lo16(u32 u){ return __uint_as_float(u << 16); }
__device__ __forceinline__ float hi16(u32 u){ return __uint_as_float(u & 0xFFFF0000u); }
__device__ __forceinline__ u16 f2bf(float f){
    u32 u = __float_as_uint(f);
    u += 0x7FFFu + ((u >> 16) & 1u);
    return (u16)(u >> 16);
}
__device__ __forceinline__ u32 pack2(float a, float b){
#if defined(__gfx950__) && __has_builtin(__builtin_amdgcn_cvt_pk_bf16_f32)
    auto r = __builtin_amdgcn_cvt_pk_bf16_f32(a, b);   // v_cvt_pk_bf16_f32 (RNE)
    return *(u32*)&r;
#else
    return (u32)f2bf(a) | ((u32)f2bf(b) << 16);
#endif
}
__device__ __forceinline__ float fexp2(float x){
#if __has_builtin(__builtin_amdgcn_exp2f)
    return __builtin_amdgcn_exp2f(x);                  // single v_exp_f32
#else
    return exp2f(x);
#endif
}
__device__ __forceinline__ void unpack8(uint4 r, float* d){
    d[0]=lo16(r.x); d[1]=hi16(r.x); d[2]=lo16(r.y); d[3]=hi16(r.y);
    d[4]=lo16(r.z); d[5]=hi16(r.z); d[6]=lo16(r.w); d[7]=hi16(r.w);
}
__device__ __forceinline__ uint4 pack8(const float* a){
    uint4 uu;
    uu.x = pack2(a[0], a[1]);
    uu.y = pack2(a[2], a[3]);
    uu.z = pack2(a[4], a[5]);
    uu.w = pack2(a[6], a[7]);
    return uu;
}
__device__ __forceinline__ float gelu_f(float x){
    return 0.5f * x * (1.0f + erff(x * 0.70710678118654752f));
}

template<int N>
__device__ __forceinline__ void store_bf16(u32* dst, const float* a){
    uint4* p4 = (uint4*)(dst);
    #pragma unroll
    for (int w4 = 0; w4 < N/8; ++w4) p4[w4] = pack8(a + 8*w4);
}

// ---------------- K0: transpose wq/wk/wv -> bf16 [n][k] (B-frag friendly) ----------------
__global__ __launch_bounds__(256, 4) void k0_wt(
    const float* __restrict__ wq, const float* __restrict__ wk,
    const float* __restrict__ wv, u16* __restrict__ wt)
{
    const int i = blockIdx.x*256 + threadIdx.x;     // 48 blocks * 256 = 12288
    const int m = i >> 12, rem = i & 4095;
    const int kk = rem >> 6, n = rem & 63;          // consecutive tid -> consecutive n (coalesced read)
    const float* w = (m==0 ? wq : (m==1 ? wk : wv));
    wt[m*4096 + n*64 + kk] = f2bf(w[kk*64 + n]);
}

// ---------------- K1: patch gather + LN1 (LDS) + MFMA QKV ----------------
// XCD-chunked patch remap: each XCD gets 64 contiguous patches (a 58-row image
// band, 3.4MB <= 4MB L2) so overlapping gather lines are L2-co-resident.
// Phase A: 2 threads/token gather x, LN1 via pair-shuffle; t written via LDS
//          staging in two 128-token rounds -> perfectly coalesced 8KB bursts
//          (eliminates partial-line write amplification + write-allocate fetch).
// Phase B: 8 waves x 2 m-tiles; per matrix: B-frags = global b128 loads of the
//          k0-transposed weights (L1-hot), 8 MFMAs, pair-pack -> per-wave strip,
//          fully-coalesced 256B stores of q/k/v.
// NOTE: q is pre-scaled by 0.25*log2(e) so k2's softmax exp2 needs no multiply.
__global__ __launch_bounds__(512, 4) void k1_qkv(
    const float* __restrict__ x, const float* __restrict__ g1, const float* __restrict__ b1,
    const u16* __restrict__ wt,
    float* __restrict__ t_out, u32* __restrict__ qo, u32* __restrict__ ko, u32* __restrict__ vo)
{
    __shared__ __align__(16) u16 ys[256*72];  // [tok][72 u16]: 64 ch + 8 pad; fp32 t-staging scratch first
    __shared__ u32 strip[8][16*34];      // per-wave 16 rows x (32 u32 + 2 pad)
    __shared__ float g_s[64], b_s[64];
    const int tid = threadIdx.x;
    if (tid < 64){ g_s[tid]=g1[tid]; b_s[tid]=b1[tid]; }

    const int bid = blockIdx.x;
    const int p = ((bid & 7) << 6) | (bid >> 3);   // XCD-chunked (bijective, 512 = 8*64)
    const int bi = p >> 8, ph = (p >> 4) & 15, pw = p & 15;

    // ---- Phase A: gather ----
    const int tok = tid >> 1, h = tid & 1;
    const int ti = tok >> 4, tj = tok & 15;
    const int r = ph*STP + ti, c = pw*STP + tj;
    const float* xb = x + ((size_t)bi*64 + 32*h)*HWIMG + (size_t)r*WW + c;

    float v32[32];
    float s1 = 0.f, s2 = 0.f;
    #pragma unroll
    for (int c8 = 0; c8 < 4; ++c8){
        #pragma unroll
        for (int u = 0; u < 8; ++u){
            const float vv = xb[(size_t)(c8*8+u)*HWIMG];
            v32[c8*8+u] = vv;
            s1 += vv; s2 += vv*vv;
        }
    }
    s1 += __shfl_xor(s1, 1);
    s2 += __shfl_xor(s2, 1);
    const float mu = s1 * (1.f/64.f);
    const float var = s2 * (1.f/64.f) - mu*mu;
    const float rs = rsqrtf(var + 1e-5f);

    // ---- staged t write: two 128-token rounds through ys scratch ----
    // stride 68 floats (272B) per token: lt*68 % 32 = lt*4 -> <=4-way write banks
    {
        float* ysf = (float*)ys;             // 128 tok * 272B = 34816B <= 36864B
        const int myrnd = tok >> 7;
        #pragma unroll
        for (int rnd = 0; rnd < 2; ++rnd){
            __syncthreads();                 // scratch free (prev round consumed)
            if (myrnd == rnd){
                const int lt = tok & 127;
                float4* dl = (float4*)(ysf + lt*68 + 32*h);
                #pragma unroll
                for (int c8 = 0; c8 < 4; ++c8){
                    dl[c8*2]   = make_float4(v32[c8*8+0],v32[c8*8+1],v32[c8*8+2],v32[c8*8+3]);
                    dl[c8*2+1] = make_float4(v32[c8*8+4],v32[c8*8+5],v32[c8*8+6],v32[c8*8+7]);
                }
            }
            __syncthreads();                 // scratch ready
            const float4* s4 = (const float4*)ysf;
            float4* d4 = (float4*)(t_out + ((size_t)p*TOK + rnd*128)*64);
            #pragma unroll
            for (int i = 0; i < 4; ++i){
                const int q = i*512 + tid;   // 2048 float4 = 32KB out
                d4[q] = s4[(q >> 4)*17 + (q & 15)];
            }
        }
    }
    __syncthreads();                         // copy-out done; ys now free for bf16

    // ---- LN -> ys (bf16) ----
    u32* ysw = (u32*)ys;
    #pragma unroll
    for (int i2 = 0; i2 < 16; ++i2){
        const int kk = 32*h + 2*i2;
        const float a0 = (v32[2*i2]  -mu)*rs*g_s[kk]   + b_s[kk];
        const float a1 = (v32[2*i2+1]-mu)*rs*g_s[kk+1] + b_s[kk+1];
        ysw[tok*36 + 16*h + i2] = pack2(a0, a1);
    }
    __syncthreads();                      // ys ready

    // ---- Phase B ----
    const int lane = tid & 63;
    const int w8   = tid >> 6;           // wave 0..7
    const int c15  = lane & 15;
    const int quad = lane >> 4;
    u32* stw = strip[w8];
    const size_t ptok = (size_t)p * TOK;

    for (int mt = 0; mt < 2; ++mt){
        const int T = w8*32 + mt*16;     // m-tile token base
        short8 af[2];
        #pragma unroll
        for (int kb = 0; kb < 2; ++kb)
            af[kb] = *(const short8*)(ys + (T + c15)*72 + kb*32 + quad*8);

        #pragma unroll
        for (int m = 0; m < 3; ++m){
            // B-frags for this matrix (b128 loads, L1/L2-hot)
            short8 bf[2][4];
            #pragma unroll
            for (int kb = 0; kb < 2; ++kb)
                #pragma unroll
                for (int nt = 0; nt < 4; ++nt)
                    bf[kb][nt] = *(const short8*)(wt + m*4096 + (nt*16 + c15)*64 + kb*32 + quad*8);

            f32x4 C[4];
            #pragma unroll
            for (int nt = 0; nt < 4; ++nt) C[nt] = (f32x4){0.f,0.f,0.f,0.f};
            #pragma unroll
            for (int kb = 0; kb < 2; ++kb)
                #pragma unroll
                for (int nt = 0; nt < 4; ++nt)
                    C[nt] = __builtin_amdgcn_mfma_f32_16x16x32_bf16(af[kb], bf[kb][nt], C[nt], 0, 0, 0);

            // fold softmax scale (dh^-0.5 * log2e) into q
            if (m == 0){
                #pragma unroll
                for (int nt = 0; nt < 4; ++nt)
                    #pragma unroll
                    for (int rr = 0; rr < 4; ++rr)
                        C[nt][rr] *= 0.3606737602222409f;
            }

            // pair-pack C tiles -> strip (b32 writes, <=2-way banks)
            #pragma unroll
            for (int nt = 0; nt < 4; ++nt){
                #pragma unroll
                for (int r2 = 0; r2 < 2; ++r2){
                    const float pv0 = __shfl_xor(C[nt][2*r2],   1);
                    const float pv1 = __shfl_xor(C[nt][2*r2+1], 1);
                    u32 wrd; int row;
                    if ((lane & 1) == 0){ wrd = pack2(C[nt][2*r2], pv0);  row = quad*4 + 2*r2; }
                    else                { wrd = pack2(pv1, C[nt][2*r2+1]); row = quad*4 + 2*r2 + 1; }
                    stw[row*34 + nt*8 + (c15 >> 1)] = wrd;
                }
            }

            // coalesced store: 8 insts x 64 lanes x 4B = 16 token rows
            u32* om = (m==0 ? qo : (m==1 ? ko : vo));
            #pragma unroll
            for (int i = 0; i < 8; ++i){
                const int flat = i*64 + lane;
                const u32 wv = stw[(flat >> 5)*34 + (flat & 31)];
                om[(ptok + T)*32 + flat] = wv;
            }
        }
    }
}

// ---------------- K2: MFMA attention (swapped QK^T), 2 blocks/patch, wave = head ----------------
// S^T = mfma(K, Q): col = q-token (lane&15) -> each lane owns one full q-row of P.
// P->LDS pack is pure in-lane cvt_pk (no shuffles); row-sum is in-lane + 2 shfl_xor.
// K and V frags RESIDENT in VGPRs. Grid split 2x over q-tiles -> 4 blocks/CU occupancy.
__global__ __launch_bounds__(256, 2) void k2_attn(
    const u16* __restrict__ qg, const u16* __restrict__ kg,
    const u16* __restrict__ vg, u16* __restrict__ og)   // og aliases qg
{
    __shared__ u16 plds[4][16*280];      // per-wave 16 q-rows x 280 u16 (560B stride)
    const int tid  = threadIdx.x;
    const int lane = tid & 63;
    const int h    = tid >> 6;           // wave = head
    const int pb   = blockIdx.x;
    const int p    = pb >> 1;            // patch
    const int half = pb & 1;             // q-tile half (0: qt 0-7, 1: qt 8-15)
    const int c15  = lane & 15;
    const int quad = lane >> 4;
    const size_t pbase = (size_t)p * TOK * 64;   // u16 elements

    // K A-frags resident (16 tiles; quads 2,3 = K-dim zero pad)
    short8 kf[16];
    #pragma unroll
    for (int t = 0; t < 16; ++t){
        short8 bf = {0,0,0,0,0,0,0,0};
        if (quad < 2)
            bf = *(const short8*)(kg + pbase + (size_t)(t*16 + c15)*64 + h*16 + quad*8);
        kf[t] = bf;
    }
    // V B-frags resident: vf[kb][j] = V[kb*32+quad*8+j][h*16+c15]
    short8 vf[8];
    #pragma unroll
    for (int kb = 0; kb < 8; ++kb){
        #pragma unroll
        for (int j = 0; j < 8; ++j)
            vf[kb][j] = (short)vg[pbase + (size_t)(kb*32 + quad*8 + j)*64 + h*16 + c15];
    }
    u16* pw  = &plds[h][0];
    u32* pwq = (u32*)pw + c15*140;       // this lane's q-row base (word units)

    for (int qi = 0; qi < 8; ++qi){
        const int qt = half*8 + qi;

        // Q B-frag (quads 2,3 are the K-pad -> zero); q pre-scaled in k1
        short8 qf = {0,0,0,0,0,0,0,0};
        if (quad < 2)
            qf = *(const short8*)(qg + pbase + (size_t)(qt*16 + c15)*64 + h*16 + quad*8);

        // S^T = K . Q^T : 16 k-tiles; lane holds P^T[k=t*16+quad*4+r][q=c15]
        f32x4 St[16];
        #pragma unroll
        for (int t = 0; t < 16; ++t){
            f32x4 z = {0.f,0.f,0.f,0.f};
            St[t] = __builtin_amdgcn_mfma_f32_16x16x32_bf16(kf[t], qf, z, 0, 0, 0);
        }

        // exp2 (scale folded into q); in-lane partial row sums
        float rsm[4] = {0.f,0.f,0.f,0.f};
        #pragma unroll
        for (int t = 0; t < 16; ++t){
            #pragma unroll
            for (int r = 0; r < 4; ++r){
                const float pe = fexp2(St[t][r]);
                St[t][r] = pe;
                rsm[r] += pe;
            }
        }
        float s = (rsm[0]+rsm[1]) + (rsm[2]+rsm[3]);
        s += __shfl_xor(s, 16);
        s += __shfl_xor(s, 32);
        const float rinv = __builtin_amdgcn_rcpf(s);
        float rv[4];
        #pragma unroll
        for (int r = 0; r < 4; ++r) rv[r] = __shfl(rinv, quad*4 + r);   // rinv for q-row quad*4+r

        // P -> LDS (bf16, unnormalized): adjacent k pairs are in-lane -> pure cvt_pk + b64 write
        #pragma unroll
        for (int t = 0; t < 16; ++t){
            uint2 wr;
            wr.x = pack2(St[t][0], St[t][1]);
            wr.y = pack2(St[t][2], St[t][3]);
            *(uint2*)(pwq + t*8 + quad*2) = wr;    // row c15, k-offset t*16+quad*4
        }

        // PV: O[q][d], A = P from LDS, B = resident V frags; two chains for ILP
        f32x4 O0 = {0.f,0.f,0.f,0.f}, O1 = {0.f,0.f,0.f,0.f};
        #pragma unroll
        for (int kb = 0; kb < 4; ++kb){
            const short8 a0 = *(const short8*)(pw + c15*280 + (2*kb)*32 + quad*8);
            const short8 a1 = *(const short8*)(pw + c15*280 + (2*kb+1)*32 + quad*8);
            O0 = __builtin_amdgcn_mfma_f32_16x16x32_bf16(a0, vf[2*kb],   O0, 0, 0, 0);
            O1 = __builtin_amdgcn_mfma_f32_16x16x32_bf16(a1, vf[2*kb+1], O1, 0, 0, 0);
        }

        // normalize rows by softmax sum (rcp) and store
        #pragma unroll
        for (int r = 0; r < 4; ++r){
            const float ov = (O0[r] + O1[r]) * rv[r];
            og[pbase + (size_t)(qt*16 + quad*4 + r)*64 + h*16 + c15] = f2bf(ov);
        }
    }
}

// ---------------- K3: MFMA proj + residual + LN2 + fc1 + GELU ----------------
__global__ __launch_bounds__(256, 2) void k3_proj_fc1(
    const u16* __restrict__ og, float* __restrict__ t,
    const float* __restrict__ wp, const float* __restrict__ bp,
    const float* __restrict__ g2, const float* __restrict__ b2,
    const float* __restrict__ wf1, const float* __restrict__ bf1,
    u32* __restrict__ y3)
{
    __shared__ u16 strip[4][16*136];     // per-wave: 16 rows x 136 u16 (272B stride)
    __shared__ float bp_s[64], g_s[64], b_s[64], bf_s[128];
    const int tid  = threadIdx.x;
    const int lane = tid & 63;
    const int w    = tid >> 6;
    const int c15  = lane & 15;
    const int quad = lane >> 4;
    if (tid < 64){ bp_s[tid]=bp[tid]; g_s[tid]=g2[tid]; b_s[tid]=b2[tid]; }
    else if (tid >= 128){ const int j = tid - 128; bf_s[j] = bf1[j]; }
    __syncthreads();

    // resident B-frags (bf16): wp 2kb x 4nt, wf1 2kb x 8nt
    short8 wpf[2][4];
    short8 wff[2][8];
    #pragma unroll
    for (int kb = 0; kb < 2; ++kb){
        #pragma unroll
        for (int nt = 0; nt < 4; ++nt){
            #pragma unroll
            for (int j = 0; j < 8; ++j)
                wpf[kb][nt][j] = (short)f2bf(wp[(kb*32 + quad*8 + j)*64 + nt*16 + c15]);
        }
        #pragma unroll
        for (int nt = 0; nt < 8; ++nt){
            #pragma unroll
            for (int j = 0; j < 8; ++j)
                wff[kb][nt][j] = (short)f2bf(wf1[(kb*32 + quad*8 + j)*128 + nt*16 + c15]);
        }
    }

    const int p = blockIdx.x;
    const size_t pbase = (size_t)p * TOK;           // token index base
    u16* st = strip[w];
    u32* stw = (u32*)st;

    const float gch[4] = { g_s[0*16+c15], g_s[1*16+c15], g_s[2*16+c15], g_s[3*16+c15] };
    const float bch[4] = { b_s[0*16+c15], b_s[1*16+c15], b_s[2*16+c15], b_s[3*16+c15] };
    const float bpc[4] = { bp_s[0*16+c15], bp_s[1*16+c15], bp_s[2*16+c15], bp_s[3*16+c15] };

    for (int rt = 0; rt < 4; ++rt){
        const int T = w*64 + rt*16;                 // m-tile token base

        // proj A-frags
        short8 af[2];
        #pragma unroll
        for (int kb = 0; kb < 2; ++kb)
            af[kb] = *(const short8*)(og + (pbase + T + c15)*64 + kb*32 + quad*8);

        // proj MFMA (bias init)
        f32x4 C[4];
        #pragma unroll
        for (int nt = 0; nt < 4; ++nt){
            const float b = bpc[nt];
            C[nt] = (f32x4){b, b, b, b};
        }
        #pragma unroll
        for (int kb = 0; kb < 2; ++kb)
            #pragma unroll
            for (int nt = 0; nt < 4; ++nt)
                C[nt] = __builtin_amdgcn_mfma_f32_16x16x32_bf16(af[kb], wpf[kb][nt], C[nt], 0, 0, 0);

        // residual add + t2 store (64B segments)
        #pragma unroll
        for (int nt = 0; nt < 4; ++nt){
            #pragma unroll
            for (int r = 0; r < 4; ++r)
                C[nt][r] += t[(pbase + T + quad*4 + r)*64 + nt*16 + c15];
        }
        #pragma unroll
        for (int nt = 0; nt < 4; ++nt){
            #pragma unroll
            for (int r = 0; r < 4; ++r)
                t[(pbase + T + quad*4 + r)*64 + nt*16 + c15] = C[nt][r];
        }

        // LN2 row stats (row = quad*4 + r)
        float rs1[4] = {0,0,0,0}, rs2[4] = {0,0,0,0};
        #pragma unroll
        for (int nt = 0; nt < 4; ++nt)
            #pragma unroll
            for (int r = 0; r < 4; ++r){ rs1[r] += C[nt][r]; rs2[r] += C[nt][r]*C[nt][r]; }
        #pragma unroll
        for (int r = 0; r < 4; ++r){
            rs1[r] += __shfl_xor(rs1[r], 1); rs2[r] += __shfl_xor(rs2[r], 1);
            rs1[r] += __shfl_xor(rs1[r], 2); rs2[r] += __shfl_xor(rs2[r], 2);
            rs1[r] += __shfl_xor(rs1[r], 4); rs2[r] += __shfl_xor(rs2[r], 4);
            rs1[r] += __shfl_xor(rs1[r], 8); rs2[r] += __shfl_xor(rs2[r], 8);
        }
        float muv[4], rsg[4];
        #pragma unroll
        for (int r = 0; r < 4; ++r){
            muv[r] = rs1[r]*(1.f/64.f);
            const float var = rs2[r]*(1.f/64.f) - muv[r]*muv[r];
            rsg[r] = rsqrtf(var + 1e-5f);
        }

        // normalized y -> strip (bf16, pair-packed b32 writes)
        #pragma unroll
        for (int nt = 0; nt < 4; ++nt){
            float yv[4];
            #pragma unroll
            for (int r = 0; r < 4; ++r)
                yv[r] = (C[nt][r]-muv[r])*rsg[r]*gch[nt] + bch[nt];
            #pragma unroll
            for (int r2 = 0; r2 < 2; ++r2){
                const float pv0 = __shfl_xor(yv[2*r2],   1);
                const float pv1 = __shfl_xor(yv[2*r2+1], 1);
                u32 wrd; int row;
                if ((lane & 1) == 0){ wrd = pack2(yv[2*r2], pv0);  row = quad*4 + 2*r2; }
                else                { wrd = pack2(pv1, yv[2*r2+1]); row = quad*4 + 2*r2 + 1; }
                *(u32*)(st + row*136 + nt*16 + (c15 & ~1)) = wrd;
            }
        }

        // fc1 A-frags from strip
        short8 pa[2];
        #pragma unroll
        for (int kb = 0; kb < 2; ++kb)
            pa[kb] = *(const short8*)(st + c15*136 + kb*32 + quad*8);

        // fc1 MFMA (bias init)
        f32x4 F[8];
        #pragma unroll
        for (int nt = 0; nt < 8; ++nt){
            const float b = bf_s[nt*16 + c15];
            F[nt] = (f32x4){b, b, b, b};
        }
        #pragma unroll
        for (int kb = 0; kb < 2; ++kb)
            #pragma unroll
            for (int nt = 0; nt < 8; ++nt)
                F[nt] = __builtin_amdgcn_mfma_f32_16x16x32_bf16(pa[kb], wff[kb][nt], F[nt], 0, 0, 0);

        // GELU
        #pragma unroll
        for (int nt = 0; nt < 8; ++nt)
            #pragma unroll
            for (int r = 0; r < 4; ++r)
                F[nt][r] = gelu_f(F[nt][r]);

        // y3 tile -> strip (pair-packed bf16)
        #pragma unroll
        for (int nt = 0; nt < 8; ++nt){
            #pragma unroll
            for (int r2 = 0; r2 < 2; ++r2){
                const float pv0 = __shfl_xor(F[nt][2*r2],   1);
                const float pv1 = __shfl_xor(F[nt][2*r2+1], 1);
                u32 wrd; int row;
                if ((lane & 1) == 0){ wrd = pack2(F[nt][2*r2], pv0);  row = quad*4 + 2*r2; }
                else                { wrd = pack2(pv1, F[nt][2*r2+1]); row = quad*4 + 2*r2 + 1; }
                *(u32*)(st + row*136 + nt*16 + (c15 & ~1)) = wrd;
            }
        }
        // coalesced y3 store: inst i covers token T+i, 64 u32 = 256B contiguous
        #pragma unroll
        for (int i = 0; i < 16; ++i){
            const u32 wv = stw[i*68 + lane];
            y3[(pbase + T + i)*64 + lane] = wv;
        }
    }
}

// ---------------- K4a: depthwise 5x5 conv + GELU + add (in-place on y3) ----------------
// thread = (column-group, channel-pair): weights in 50 regs (zero LDS weight reads),
// 5x5 sliding register window down each column (5 LDS reads/output, conflict-free:
// lanes 0..31 read consecutive ch2 words), natively coalesced 128B-segment stores.
__global__ __launch_bounds__(256, 2) void k4a_dwconv(
    u32* y3, const float* __restrict__ wdw, const float* __restrict__ bdw)
{
    __shared__ u32 ys[400*33];       // 20x20 zero halo, 32 u32 (one half) + 1 pad
    const int tid = threadIdx.x;
    const int p = blockIdx.x;
    const int ch2 = tid & 31;        // channel pair within the half
    const int cg  = tid >> 5;        // 0..7 -> image columns 2cg, 2cg+1
    const size_t ptok = (size_t)p * TOK;

    // token mapping for the fill phase (thread = token)
    const int fti = tid >> 4, ftj = tid & 15;
    const int fstok = (fti+2)*20 + (ftj+2);

    for (int i = tid; i < 13200; i += 256) ys[i] = 0u;

    for (int half = 0; half < 2; ++half){
        __syncthreads();             // zero-init done / previous half's readers done
        // fill halo interior: 32 words of this half per token (coalesced b128 reads)
        {
            const uint4* gp = (const uint4*)(y3 + (ptok + tid)*64 + half*32);
            #pragma unroll
            for (int w = 0; w < 8; ++w){
                uint4 rr = gp[w];
                ys[fstok*33 + w*4+0]=rr.x; ys[fstok*33 + w*4+1]=rr.y;
                ys[fstok*33 + w*4+2]=rr.z; ys[fstok*33 + w*4+3]=rr.w;
            }
        }
        // weights -> 50 regs (L1/L2-hot, 12.8KB total)
        float wA[25], wB[25];
        #pragma unroll
        for (int tap = 0; tap < 25; ++tap){
            wA[tap] = wdw[(half*64 + 2*ch2+0)*25 + tap];
            wB[tap] = wdw[(half*64 + 2*ch2+1)*25 + tap];
        }
        const float bA = bdw[half*64 + 2*ch2+0];
        const float bB = bdw[half*64 + 2*ch2+1];
        __syncthreads();             // ys ready

        #pragma unroll
        for (int cc = 0; cc < 2; ++cc){
            const int c  = cg*2 + cc;          // image column 0..15
            const int hc = c + 2;              // halo column of the center
            u32 win[5][5];                     // halo rows (mod 5) x 5 tap cols
            #pragma unroll
            for (int r = 0; r < 4; ++r)
                #pragma unroll
                for (int j = 0; j < 5; ++j)
                    win[r][j] = ys[(r*20 + hc-2+j)*33 + ch2];
            #pragma unroll
            for (int row = 0; row < 16; ++row){
                #pragma unroll
                for (int j = 0; j < 5; ++j)
                    win[(row+4)%5][j] = ys[((row+4)*20 + hc-2+j)*33 + ch2];
                float a0 = bA, a1 = bB;
                #pragma unroll
                for (int di = 0; di < 5; ++di){
                    #pragma unroll
                    for (int dj = 0; dj < 5; ++dj){
                        const u32 v = win[(row+di)%5][dj];
                        a0 += lo16(v)*wA[di*5+dj];
                        a1 += hi16(v)*wB[di*5+dj];
                    }
                }
                const u32 own = win[(row+2)%5][2];   // center pixel, free residual
                const float o0 = lo16(own) + gelu_f(a0);
                const float o1 = hi16(own) + gelu_f(a1);
                // coalesced: lanes 0..31 = ch2 0..31 -> one 128B segment per token
                y3[(ptok + row*16 + c)*64 + half*32 + ch2] = pack2(o0, o1);
            }
        }
    }
}

// ---------------- K4b: MFMA fc2 + residual -> t3 [patch][ch][tok] ----------------
// 128->64 GEMM per token. wf2 resident as bf16 B-frags (no LDS, no spills);
// y3 rows load directly as A-frags (channel-major bf16, K=128 = 4 kb blocks).
__global__ __launch_bounds__(256, 2) void k4b_fc2(
    const u16* __restrict__ y3h, const float* __restrict__ t2,
    const float* __restrict__ wf2, const float* __restrict__ bf2,
    float* __restrict__ t3)
{
    const int tid  = threadIdx.x;
    const int lane = tid & 63;
    const int w    = tid >> 6;
    const int c15  = lane & 15;
    const int quad = lane >> 4;

    // resident B-frags: wf2 [128][64] fp32 -> bf16; kb over K=128, nt over N=64
    short8 wf[4][4];
    #pragma unroll
    for (int kb = 0; kb < 4; ++kb)
        #pragma unroll
        for (int nt = 0; nt < 4; ++nt)
            #pragma unroll
            for (int j = 0; j < 8; ++j)
                wf[kb][nt][j] = (short)f2bf(wf2[(kb*32 + quad*8 + j)*64 + nt*16 + c15]);

    float bcc[4];
    #pragma unroll
    for (int nt = 0; nt < 4; ++nt) bcc[nt] = bf2[nt*16 + c15];

    const int p = blockIdx.x;
    const size_t pbase = (size_t)p * TOK;
    float* t3p = t3 + (size_t)p * 16384;

    for (int rt = 0; rt < 4; ++rt){
        const int T = w*64 + rt*16;                // m-tile token base

        // A-frags: token rows of y3 (128 bf16 channels contiguous)
        short8 af[4];
        #pragma unroll
        for (int kb = 0; kb < 4; ++kb)
            af[kb] = *(const short8*)(y3h + (pbase + T + c15)*128 + kb*32 + quad*8);

        // MFMA with bias init
        f32x4 C[4];
        #pragma unroll
        for (int nt = 0; nt < 4; ++nt){
            const float b = bcc[nt];
            C[nt] = (f32x4){b, b, b, b};
        }
        #pragma unroll
        for (int kb = 0; kb < 4; ++kb)
            #pragma unroll
            for (int nt = 0; nt < 4; ++nt)
                C[nt] = __builtin_amdgcn_mfma_f32_16x16x32_bf16(af[kb], wf[kb][nt], C[nt], 0, 0, 0);

        // residual add (t2 fp32, token-major)
        #pragma unroll
        for (int nt = 0; nt < 4; ++nt)
            #pragma unroll
            for (int r = 0; r < 4; ++r)
                C[nt][r] += t2[(pbase + T + quad*4 + r)*64 + nt*16 + c15];

        // store t3 [ch][tok]: per (nt,r) inst, 16 chans x 16B chunks; 4 r-insts
        // tile each channel's 64B token line -> merged in write-back L2
        #pragma unroll
        for (int nt = 0; nt < 4; ++nt)
            #pragma unroll
            for (int r = 0; r < 4; ++r)
                t3p[(nt*16 + c15)*256 + T + quad*4 + r] = C[nt][r];
    }
}

// ---------------- K5: overlap-add gather + averaging ----------------
__global__ __launch_bounds__(256, 4) void k5_reverse(
    const float* __restrict__ t3, float* __restrict__ out)
{
    const int e = blockIdx.x*256 + threadIdx.x;
    if (e >= OUT_ELEMS) return;
    const int c = e % WW;
    int tmp = e / WW;
    const int r = tmp % HH;
    tmp /= HH;
    const int ch = tmp & 63;
    const int b = tmp >> 6;
    int pr = r/14; if (pr > 15) pr = 15;
    int pc = c/14; if (pc > 15) pc = 15;
    const int ra = r - pr*14, ca = c - pc*14;
    const int rb = ra + 14, cb = ca + 14;
    const bool hr = (pr >= 1) && (rb < 16);
    const bool hc = (pc >= 1) && (cb < 16);
    #define T3IDX(PH,PC,I,J) (((((b*16+(PH))*16+(PC))*64 + ch) << 8) + (I)*16 + (J))
    float s = t3[T3IDX(pr,pc,ra,ca)];
    if (hr)       s += t3[T3IDX(pr-1,pc,  rb,ca)];
    if (hc)       s += t3[T3IDX(pr,  pc-1,ra,cb)];
    if (hr && hc) s += t3[T3IDX(pr-1,pc-1,rb,cb)];
    const float f = (hr ? 0.5f : 1.f) * (hc ? 0.5f : 1.f);
    out[e] = s * f;
    #undef T3IDX
}

extern "C" void kernel_launch(void* const* d_in, const int* in_sizes, int n_in,
                              void* d_out, int out_size, void* d_ws, size_t ws_size,
                              hipStream_t stream)
{
    const float* x    = (const float*)d_in[0];
    const float* g1   = (const float*)d_in[1];
    const float* b1   = (const float*)d_in[2];
    const float* wq   = (const float*)d_in[3];
    const float* wk   = (const float*)d_in[4];
    const float* wv   = (const float*)d_in[5];
    const float* wp   = (const float*)d_in[6];
    const float* bp   = (const float*)d_in[7];
    const float* g2   = (const float*)d_in[8];
    const float* b2   = (const float*)d_in[9];
    const float* wf1  = (const float*)d_in[10];
    const float* bf1  = (const float*)d_in[11];
    const float* wdw  = (const float*)d_in[12];
    const float* bdw  = (const float*)d_in[13];
    const float* wf2  = (const float*)d_in[14];
    const float* bf2  = (const float*)d_in[15];

    char* ws = (char*)d_ws;
    // layout (bytes):
    //   [0,        33554432)  t   fp32  (becomes t2 in-place in k3)
    //   [33554432, 50331648)  q   bf16  (k2 output o overwrites it)
    //   [50331648, 67108864)  k   bf16  \  t3 fp32 aliases k+v after k2
    //   [67108864, 83886080)  v   bf16  /
    //   [83886080, 117440512) y3  bf16  (128/token; k4a updates in place)
    // wt (transposed bf16 qkv weights, 24 KB) lives at the head of d_out —
    // consumed by k1, fully overwritten by k5 at the end.
    float* t  = (float*)(ws);
    u32* q    = (u32*)(ws + 33554432);
    u32* k    = (u32*)(ws + 50331648);
    u32* v    = (u32*)(ws + 67108864);
    float* t3 = (float*)(ws + 50331648);
    u32* y3   = (u32*)(ws + 83886080);
    u16* wt   = (u16*)d_out;
    float* out = (float*)d_out;

    k0_wt      <<<48,        256, 0, stream>>>(wq, wk, wv, wt);
    k1_qkv     <<<NPATCH,    512, 0, stream>>>(x, g1, b1, wt, t, q, k, v);
    k2_attn    <<<NPATCH*2,  256, 0, stream>>>((const u16*)q, (const u16*)k, (const u16*)v, (u16*)q);
    k3_proj_fc1<<<NPATCH,    256, 0, stream>>>((const u16*)q, t, wp, bp, g2, b2, wf1, bf1, y3);
    k4a_dwconv <<<NPATCH,    256, 0, stream>>>(y3, wdw, bdw);
    k4b_fc2    <<<NPATCH,    256, 0, stream>>>((const u16*)y3, t, wf2, bf2, t3);
    k5_reverse <<<25538,     256, 0, stream>>>(t3, out);
}